// Round 1
// baseline (15127.884 us; speedup 1.0000x reference)
//
#include <hip/hip_runtime.h>
#include <hip/hip_bf16.h>

#define B_      4
#define TT_     128
#define TA_     512
#define TE_     225
#define T_      865
#define D_      1024
#define H_      16
#define HD_     64
#define FF_     4096
#define L_      6
#define PREFIX_ 640
#define M_TOK   (B_ * T_)   // 3460

// ---------------------------------------------------------------------------
// Embedding + pack + sinusoidal PE. One block per (b, pos) token row.
// ---------------------------------------------------------------------------
__global__ __launch_bounds__(256) void embed_kernel(
    const int* __restrict__ text, const int* __restrict__ audio,
    const int* __restrict__ enrolled, const int* __restrict__ tl_b,
    const int* __restrict__ al_b, const float* __restrict__ text_emb,
    const float* __restrict__ audio_emb,
    float* __restrict__ x, float* __restrict__ mem) {
  int row = blockIdx.x;            // b*T + pos
  int b = row / T_, pos = row - b * T_;
  int tl = tl_b[b], al = al_b[b];
  const float* emb = nullptr;
  int p = 0;
  if (pos < tl) {
    emb = text_emb + (size_t)text[b * TT_ + pos] * D_;
    p = pos;
  } else if (pos < tl + al) {
    emb = audio_emb + (size_t)audio[b * TA_ + (pos - tl)] * D_;
    p = pos - tl;
  } else if (pos < tl + al + TE_) {
    emb = audio_emb + (size_t)enrolled[b * TE_ + (pos - tl - al)] * D_;
    p = pos - tl - al;
  }
  int d0 = threadIdx.x * 4;
  float4 v;
  float* pv = (float*)&v;
  if (emb) {
    const float c = -9.2103403719761836f / (float)D_;  // -ln(10000)/D
    #pragma unroll
    for (int e = 0; e < 4; ++e) {
      int d = d0 + e;
      int i = d >> 1;
      float freq = expf(c * (float)(2 * i));
      float arg = (float)p * freq;
      float pe = (d & 1) ? cosf(arg) : sinf(arg);
      pv[e] = emb[d] + pe;
    }
  } else {
    v = make_float4(0.f, 0.f, 0.f, 0.f);
  }
  *(float4*)&x[(size_t)row * D_ + d0] = v;
  *(float4*)&mem[(size_t)row * D_ + d0] = v;
}

// ---------------------------------------------------------------------------
// C[M,N] = A[M,K] @ W[N,K]^T + bias ; ACT==1 -> relu. 64x64 tile, K-step 16.
// ---------------------------------------------------------------------------
template <int ACT>
__global__ __launch_bounds__(256) void gemm_kernel(
    const float* __restrict__ A, int lda,
    const float* __restrict__ W,          // (N, K) row-major, ldw = K
    const float* __restrict__ bias,
    float* __restrict__ C, int ldc,
    int M, int N, int K) {
  __shared__ float As[16][64];
  __shared__ float Ws[16][64];
  int tid = threadIdx.x;
  int m0 = blockIdx.y * 64, n0 = blockIdx.x * 64;
  float acc[4][4] = {};

  int lr = tid >> 2;         // 0..63 load row within tile
  int lk = (tid & 3) * 4;    // k sub-offset
  int arow = m0 + lr;
  if (arow >= M) arow = M - 1;               // clamp; result row discarded
  const float* Aptr = A + (size_t)arow * lda;
  const float* Wptr = W + (size_t)(n0 + lr) * K;

  int mi0 = (tid >> 4) << 2;
  int ni0 = (tid & 15) << 2;

  for (int k0 = 0; k0 < K; k0 += 16) {
    float4 a4 = *(const float4*)(Aptr + k0 + lk);
    float4 w4 = *(const float4*)(Wptr + k0 + lk);
    __syncthreads();
    As[lk + 0][lr] = a4.x; As[lk + 1][lr] = a4.y;
    As[lk + 2][lr] = a4.z; As[lk + 3][lr] = a4.w;
    Ws[lk + 0][lr] = w4.x; Ws[lk + 1][lr] = w4.y;
    Ws[lk + 2][lr] = w4.z; Ws[lk + 3][lr] = w4.w;
    __syncthreads();
    #pragma unroll
    for (int kk = 0; kk < 16; ++kk) {
      float a_[4], w_[4];
      *(float4*)a_ = *(const float4*)&As[kk][mi0];
      *(float4*)w_ = *(const float4*)&Ws[kk][ni0];
      #pragma unroll
      for (int i = 0; i < 4; ++i)
        #pragma unroll
        for (int j = 0; j < 4; ++j)
          acc[i][j] += a_[i] * w_[j];
    }
  }

  #pragma unroll
  for (int i = 0; i < 4; ++i) {
    int m = m0 + mi0 + i;
    if (m < M) {
      float4 o;
      float* po = (float*)&o;
      #pragma unroll
      for (int j = 0; j < 4; ++j) {
        float vv = acc[i][j] + bias[n0 + ni0 + j];
        if (ACT == 1) vv = fmaxf(vv, 0.f);
        po[j] = vv;
      }
      *(float4*)&C[(size_t)m * ldc + n0 + ni0] = o;
    }
  }
}

// ---------------------------------------------------------------------------
// Fused flash-style attention. qkv: (B*T, 3D) rows; q cols [0,1024),
// k cols [1024,2048), v cols [2048,3072); head h occupies h*64..h*64+63.
// Grid: (ceil(T/32), B*H). 256 threads; thread owns q-row ql = tid>>3 and
// 8 strided columns c_j = (tid&7) + 8*j.
// ---------------------------------------------------------------------------
template <bool MASKED>
__global__ __launch_bounds__(256) void attn_kernel(
    const float* __restrict__ qkv,
    float* __restrict__ out) {
  __shared__ float Qs[32][68];
  __shared__ float Ks[64][68];
  __shared__ float Vs[64][68];
  __shared__ float Ps[32][68];
  int bh = blockIdx.y;
  int b = bh >> 4, h = bh & 15;
  int q0 = blockIdx.x * 32;
  int tid = threadIdx.x;
  int ql = tid >> 3;   // 0..31
  int cl = tid & 7;    // 0..7

  // load Q tile (32 x 64)
  {
    int r = tid >> 3;
    int c = (tid & 7) * 4;
    int qr = q0 + r;
    if (qr >= T_) qr = T_ - 1;
    const float* qb = qkv + ((size_t)(b * T_ + qr)) * 3072 + h * 64;
    *(float4*)&Qs[r][c]      = *(const float4*)(qb + c);
    *(float4*)&Qs[r][c + 32] = *(const float4*)(qb + c + 32);
  }

  float m = -INFINITY, l = 0.f;
  float o[8] = {};
  int qmax = q0 + 31;

  for (int k0 = 0; k0 < T_; k0 += 64) {
    if (MASKED && k0 > qmax && k0 >= PREFIX_) break;
    __syncthreads();  // protect previous iteration's LDS reads
    {
      int r = tid >> 2, c4 = (tid & 3) * 4;
      int kr = k0 + r;
      bool ok = kr < T_;
      const float* kb = qkv + ((size_t)(b * T_ + (ok ? kr : 0))) * 3072 + 1024 + h * 64;
      #pragma unroll
      for (int cc = 0; cc < 4; ++cc) {
        int col = c4 + cc * 16;
        float4 kv = ok ? *(const float4*)(kb + col)        : make_float4(0, 0, 0, 0);
        float4 vv = ok ? *(const float4*)(kb + 1024 + col) : make_float4(0, 0, 0, 0);
        *(float4*)&Ks[r][col] = kv;
        *(float4*)&Vs[r][col] = vv;
      }
    }
    __syncthreads();

    // S = Q K^T for 8 strided columns
    float s[8];
    #pragma unroll
    for (int j = 0; j < 8; ++j) s[j] = 0.f;
    #pragma unroll 4
    for (int k4 = 0; k4 < 16; ++k4) {
      float4 q4 = *(const float4*)&Qs[ql][k4 * 4];
      #pragma unroll
      for (int j = 0; j < 8; ++j) {
        float4 kk4 = *(const float4*)&Ks[cl + 8 * j][k4 * 4];
        s[j] += q4.x * kk4.x + q4.y * kk4.y + q4.z * kk4.z + q4.w * kk4.w;
      }
    }

    int q = q0 + ql;
    float tm = -INFINITY;
    #pragma unroll
    for (int j = 0; j < 8; ++j) {
      int kg = k0 + cl + 8 * j;
      float sv = s[j] * 0.125f;
      bool bad = (kg >= T_) || (MASKED && kg > q && kg >= PREFIX_);
      sv = bad ? -INFINITY : sv;
      s[j] = sv;
      tm = fmaxf(tm, sv);
    }
    tm = fmaxf(tm, __shfl_xor(tm, 1));
    tm = fmaxf(tm, __shfl_xor(tm, 2));
    tm = fmaxf(tm, __shfl_xor(tm, 4));

    float mn = fmaxf(m, tm);
    float alpha = __expf(m - mn);     // m=-inf only on first tile, mn finite
    float p[8], psum = 0.f;
    #pragma unroll
    for (int j = 0; j < 8; ++j) {
      p[j] = __expf(s[j] - mn);
      psum += p[j];
    }
    psum += __shfl_xor(psum, 1);
    psum += __shfl_xor(psum, 2);
    psum += __shfl_xor(psum, 4);
    l = l * alpha + psum;
    m = mn;
    #pragma unroll
    for (int j = 0; j < 8; ++j) o[j] *= alpha;
    #pragma unroll
    for (int j = 0; j < 8; ++j) Ps[ql][cl + 8 * j] = p[j];
    __syncthreads();

    // O += P @ V
    for (int k = 0; k < 64; ++k) {
      float pvv = Ps[ql][k];
      #pragma unroll
      for (int j = 0; j < 8; ++j) o[j] += pvv * Vs[k][cl + 8 * j];
    }
  }

  float inv = 1.f / l;
  int q = q0 + ql;
  if (q < T_) {
    float* ob = out + ((size_t)(b * T_ + q)) * D_ + h * 64;
    #pragma unroll
    for (int j = 0; j < 8; ++j) ob[cl + 8 * j] = o[j] * inv;
  }
}

// ---------------------------------------------------------------------------
// x = LayerNorm(x + r) * w + b   (row = block)
// ---------------------------------------------------------------------------
__global__ __launch_bounds__(256) void ln_res_kernel(
    float* __restrict__ x, const float* __restrict__ r,
    const float* __restrict__ w, const float* __restrict__ b) {
  __shared__ float red[4];
  int row = blockIdx.x, tid = threadIdx.x;
  float4 xv = *(float4*)&x[(size_t)row * D_ + tid * 4];
  float4 rv = *(const float4*)&r[(size_t)row * D_ + tid * 4];
  float v0 = xv.x + rv.x, v1 = xv.y + rv.y, v2 = xv.z + rv.z, v3 = xv.w + rv.w;

  float s = v0 + v1 + v2 + v3;
  #pragma unroll
  for (int off = 1; off < 64; off <<= 1) s += __shfl_xor(s, off);
  if ((tid & 63) == 0) red[tid >> 6] = s;
  __syncthreads();
  float mu = (red[0] + red[1] + red[2] + red[3]) * (1.f / 1024.f);
  __syncthreads();

  float d0 = v0 - mu, d1 = v1 - mu, d2 = v2 - mu, d3 = v3 - mu;
  float ss = d0 * d0 + d1 * d1 + d2 * d2 + d3 * d3;
  #pragma unroll
  for (int off = 1; off < 64; off <<= 1) ss += __shfl_xor(ss, off);
  if ((tid & 63) == 0) red[tid >> 6] = ss;
  __syncthreads();
  float var = (red[0] + red[1] + red[2] + red[3]) * (1.f / 1024.f);
  float rs = rsqrtf(var + 1e-5f);

  float4 wv = *(const float4*)&w[tid * 4];
  float4 bv = *(const float4*)&b[tid * 4];
  float4 ov = make_float4(d0 * rs * wv.x + bv.x, d1 * rs * wv.y + bv.y,
                          d2 * rs * wv.z + bv.z, d3 * rs * wv.w + bv.w);
  *(float4*)&x[(size_t)row * D_ + tid * 4] = ov;
}

// ---------------------------------------------------------------------------
static inline void launch_gemm(const float* A, int lda, const float* W,
                               const float* bias, float* C, int ldc,
                               int M, int N, int K, int act, hipStream_t s) {
  dim3 g(N / 64, (M + 63) / 64);
  if (act)
    gemm_kernel<1><<<g, 256, 0, s>>>(A, lda, W, bias, C, ldc, M, N, K);
  else
    gemm_kernel<0><<<g, 256, 0, s>>>(A, lda, W, bias, C, ldc, M, N, K);
}

extern "C" void kernel_launch(void* const* d_in, const int* in_sizes, int n_in,
                              void* d_out, int out_size, void* d_ws, size_t ws_size,
                              hipStream_t stream) {
  const int* text       = (const int*)d_in[0];
  const int* audio      = (const int*)d_in[1];
  const int* enrolled   = (const int*)d_in[2];
  const int* tl_b       = (const int*)d_in[3];
  const int* al_b       = (const int*)d_in[4];
  const float* text_emb = (const float*)d_in[5];
  const float* audio_emb= (const float*)d_in[6];
  const float* sa_in_w  = (const float*)d_in[7];
  const float* sa_in_b  = (const float*)d_in[8];
  const float* sa_out_w = (const float*)d_in[9];
  const float* sa_out_b = (const float*)d_in[10];
  const float* ca_in_w  = (const float*)d_in[11];
  const float* ca_in_b  = (const float*)d_in[12];
  const float* ca_out_w = (const float*)d_in[13];
  const float* ca_out_b = (const float*)d_in[14];
  const float* ff1_w    = (const float*)d_in[15];
  const float* ff1_b    = (const float*)d_in[16];
  const float* ff2_w    = (const float*)d_in[17];
  const float* ff2_b    = (const float*)d_in[18];
  const float* ln1_w    = (const float*)d_in[19];
  const float* ln1_b    = (const float*)d_in[20];
  const float* ln2_w    = (const float*)d_in[21];
  const float* ln2_b    = (const float*)d_in[22];
  const float* ln3_w    = (const float*)d_in[23];
  const float* ln3_b    = (const float*)d_in[24];
  const float* out_w    = (const float*)d_in[25];
  const float* out_b    = (const float*)d_in[26];

  float* ws = (float*)d_ws;
  float* x     = ws;                                   // M_TOK * 1024
  float* mem   = x     + (size_t)M_TOK * D_;           // M_TOK * 1024
  float* big   = mem   + (size_t)M_TOK * D_;           // M_TOK * 4096 (qkv / ffn)
  float* attno = big   + (size_t)M_TOK * FF_;          // M_TOK * 1024
  float* tmp   = attno + (size_t)M_TOK * D_;           // M_TOK * 1024

  embed_kernel<<<M_TOK, 256, 0, stream>>>(text, audio, enrolled, tl_b, al_b,
                                          text_emb, audio_emb, x, mem);

  for (int l = 0; l < L_; ++l) {
    const float* sa_in_w_l  = sa_in_w  + (size_t)l * 3 * D_ * D_;
    const float* sa_in_b_l  = sa_in_b  + (size_t)l * 3 * D_;
    const float* sa_out_w_l = sa_out_w + (size_t)l * D_ * D_;
    const float* sa_out_b_l = sa_out_b + (size_t)l * D_;
    const float* ca_in_w_l  = ca_in_w  + (size_t)l * 3 * D_ * D_;
    const float* ca_in_b_l  = ca_in_b  + (size_t)l * 3 * D_;
    const float* ca_out_w_l = ca_out_w + (size_t)l * D_ * D_;
    const float* ca_out_b_l = ca_out_b + (size_t)l * D_;
    const float* ff1_w_l    = ff1_w    + (size_t)l * FF_ * D_;
    const float* ff1_b_l    = ff1_b    + (size_t)l * FF_;
    const float* ff2_w_l    = ff2_w    + (size_t)l * D_ * FF_;
    const float* ff2_b_l    = ff2_b    + (size_t)l * D_;

    // ---- self attention ----
    launch_gemm(x, D_, sa_in_w_l, sa_in_b_l, big, 3 * D_, M_TOK, 3 * D_, D_, 0, stream);
    attn_kernel<true><<<dim3(28, B_ * H_), 256, 0, stream>>>(big, attno);
    launch_gemm(attno, D_, sa_out_w_l, sa_out_b_l, tmp, D_, M_TOK, D_, D_, 0, stream);
    ln_res_kernel<<<M_TOK, 256, 0, stream>>>(x, tmp, ln1_w + l * D_, ln1_b + l * D_);

    // ---- cross attention ----
    launch_gemm(x, D_, ca_in_w_l, ca_in_b_l, big, 3 * D_, M_TOK, D_, D_, 0, stream);  // q
    launch_gemm(mem, D_, ca_in_w_l + (size_t)D_ * D_, ca_in_b_l + D_,
                big + D_, 3 * D_, M_TOK, 2 * D_, D_, 0, stream);                      // k,v
    attn_kernel<false><<<dim3(28, B_ * H_), 256, 0, stream>>>(big, attno);
    launch_gemm(attno, D_, ca_out_w_l, ca_out_b_l, tmp, D_, M_TOK, D_, D_, 0, stream);
    ln_res_kernel<<<M_TOK, 256, 0, stream>>>(x, tmp, ln2_w + l * D_, ln2_b + l * D_);

    // ---- feed forward ----
    launch_gemm(x, D_, ff1_w_l, ff1_b_l, big, FF_, M_TOK, FF_, D_, 1, stream);
    launch_gemm(big, FF_, ff2_w_l, ff2_b_l, tmp, D_, M_TOK, D_, FF_, 0, stream);
    ln_res_kernel<<<M_TOK, 256, 0, stream>>>(x, tmp, ln3_w + l * D_, ln3_b + l * D_);
  }

  // final projection -> d_out
  launch_gemm(x, D_, out_w, out_b, (float*)d_out, 1024, M_TOK, 1024, D_, 0, stream);
}

// Round 2
// 6308.105 us; speedup vs baseline: 2.3982x; 2.3982x over previous
//
#include <hip/hip_runtime.h>
#include <hip/hip_bf16.h>

#define B_      4
#define TT_     128
#define TA_     512
#define TE_     225
#define T_      865
#define D_      1024
#define H_      16
#define FF_     4096
#define L_      6
#define PREFIX_ 640
#define M_TOK   (B_ * T_)   // 3460
#define M_PAD   3584        // 28 * 128

typedef __attribute__((ext_vector_type(8))) short          s16x8;
typedef __attribute__((ext_vector_type(4))) float          f32x4;
typedef __attribute__((ext_vector_type(8))) unsigned short u16x8;

typedef __attribute__((address_space(1))) const void gv_t;
typedef __attribute__((address_space(3))) void       lv_t;

__device__ __forceinline__ float bf2f(unsigned short u) {
  union { unsigned int i; float f; } c; c.i = ((unsigned int)u) << 16; return c.f;
}
__device__ __forceinline__ unsigned short f2bf(float f) {
  union { __hip_bfloat16 h; unsigned short u; } c; c.h = __float2bfloat16(f); return c.u;
}

// ---------------------------------------------------------------------------
// Embedding + pack + PE. Grid = M_PAD rows; padded rows zero the bf16 bufs.
// ---------------------------------------------------------------------------
__global__ __launch_bounds__(256) void embed_kernel(
    const int* __restrict__ text, const int* __restrict__ audio,
    const int* __restrict__ enrolled, const int* __restrict__ tl_b,
    const int* __restrict__ al_b, const float* __restrict__ text_emb,
    const float* __restrict__ audio_emb,
    float* __restrict__ xf, unsigned short* __restrict__ xb,
    unsigned short* __restrict__ memb, unsigned short* __restrict__ attnb) {
  int row = blockIdx.x;
  int d0 = threadIdx.x * 4;
  size_t off = (size_t)row * D_ + d0;
  if (row >= M_TOK) {
    *(unsigned long long*)&xb[off]    = 0ull;
    *(unsigned long long*)&memb[off]  = 0ull;
    *(unsigned long long*)&attnb[off] = 0ull;
    return;
  }
  int b = row / T_, pos = row - b * T_;
  int tl = tl_b[b], al = al_b[b];
  const float* emb = nullptr;
  int p = 0;
  if (pos < tl) {
    emb = text_emb + (size_t)text[b * TT_ + pos] * D_;
    p = pos;
  } else if (pos < tl + al) {
    emb = audio_emb + (size_t)audio[b * TA_ + (pos - tl)] * D_;
    p = pos - tl;
  } else if (pos < tl + al + TE_) {
    emb = audio_emb + (size_t)enrolled[b * TE_ + (pos - tl - al)] * D_;
    p = pos - tl - al;
  }
  float4 v;
  float* pv = (float*)&v;
  if (emb) {
    const float c = -9.2103403719761836f / (float)D_;  // -ln(10000)/D
    #pragma unroll
    for (int e = 0; e < 4; ++e) {
      int d = d0 + e;
      int i = d >> 1;
      float freq = expf(c * (float)(2 * i));
      float arg = (float)p * freq;
      float pe = (d & 1) ? cosf(arg) : sinf(arg);
      pv[e] = emb[d] + pe;
    }
  } else {
    v = make_float4(0.f, 0.f, 0.f, 0.f);
  }
  *(float4*)&xf[off] = v;
  unsigned long long pk = (unsigned long long)f2bf(pv[0])
      | ((unsigned long long)f2bf(pv[1]) << 16)
      | ((unsigned long long)f2bf(pv[2]) << 32)
      | ((unsigned long long)f2bf(pv[3]) << 48);
  *(unsigned long long*)&xb[off]   = pk;
  *(unsigned long long*)&memb[off] = pk;
}

// ---------------------------------------------------------------------------
// fp32 -> bf16 converters (weights). 8 elems / thread.
// ---------------------------------------------------------------------------
__global__ __launch_bounds__(256) void cvt_kernel(
    const float* __restrict__ in, unsigned short* __restrict__ out, int n8) {
  int i = blockIdx.x * 256 + threadIdx.x;
  if (i >= n8) return;
  const float4* pp = (const float4*)in + (size_t)i * 2;
  float4 a = pp[0], bq = pp[1];
  u16x8 o;
  o[0] = f2bf(a.x);  o[1] = f2bf(a.y);  o[2] = f2bf(a.z);  o[3] = f2bf(a.w);
  o[4] = f2bf(bq.x); o[5] = f2bf(bq.y); o[6] = f2bf(bq.z); o[7] = f2bf(bq.w);
  *(u16x8*)(out + (size_t)i * 8) = o;
}

// All 6 weight matrices of one layer -> wbuf (16,777,216 elems total).
__global__ __launch_bounds__(256) void cvt_layer_kernel(
    const float* __restrict__ s0, const float* __restrict__ s1,
    const float* __restrict__ s2, const float* __restrict__ s3,
    const float* __restrict__ s4, const float* __restrict__ s5,
    unsigned short* __restrict__ dst) {
  size_t e = ((size_t)blockIdx.x * 256 + threadIdx.x) * 8;
  if (e >= 16777216u) return;
  const float* src; size_t off;
  if      (e <  3145728u) { src = s0; off = e; }
  else if (e <  4194304u) { src = s1; off = e -  3145728u; }
  else if (e <  7340032u) { src = s2; off = e -  4194304u; }
  else if (e <  8388608u) { src = s3; off = e -  7340032u; }
  else if (e < 12582912u) { src = s4; off = e -  8388608u; }
  else                    { src = s5; off = e - 12582912u; }
  const float4* pp = (const float4*)(src + off);
  float4 a = pp[0], bq = pp[1];
  u16x8 o;
  o[0] = f2bf(a.x);  o[1] = f2bf(a.y);  o[2] = f2bf(a.z);  o[3] = f2bf(a.w);
  o[4] = f2bf(bq.x); o[5] = f2bf(bq.y); o[6] = f2bf(bq.z); o[7] = f2bf(bq.w);
  *(u16x8*)(dst + e) = o;
}

// ---------------------------------------------------------------------------
// bf16 MFMA GEMM (m97 structure): C[M,N] = A[M,K] @ W[N,K]^T + bias.
// 128x128 tile, BK=32, 4 waves (2x2), 16x16x32 MFMA, global_load_lds w=16.
// ACT: relu. OBF: bf16 output (else fp32).
// ---------------------------------------------------------------------------
template <int ACT, int OBF>
__global__ __launch_bounds__(256) void gemm_bf16(
    const unsigned short* __restrict__ A, int lda,
    const unsigned short* __restrict__ W, int ldw,
    const float* __restrict__ bias,
    float* __restrict__ Cf, unsigned short* __restrict__ Cb, int ldc,
    int Mw, int K) {
  __shared__ unsigned short lgA[128 * 32];   // [row][k] row-major
  __shared__ unsigned short lgB[128 * 32];
  int tid = threadIdx.x;
  int lane = tid & 63, wid = tid >> 6;
  int m0 = blockIdx.y * 128, n0 = blockIdx.x * 128;
  int wr = wid >> 1, wc = wid & 1;

  // staging: wave wid owns rows [wid*32, wid*32+32); lane covers 16B
  int lrow = lane >> 2;          // 0..15 within 16-row chunk
  int lk   = (lane & 3) * 8;     // k element offset
  const unsigned short* gA0 = A + (size_t)(m0 + wid * 32 + lrow) * lda + lk;
  const unsigned short* gA1 = gA0 + (size_t)16 * lda;
  const unsigned short* gB0 = W + (size_t)(n0 + wid * 32 + lrow) * ldw + lk;
  const unsigned short* gB1 = gB0 + (size_t)16 * ldw;
  unsigned short* lA0 = lgA + wid * 1024;        // wave-uniform bases
  unsigned short* lA1 = lA0 + 512;
  unsigned short* lB0 = lgB + wid * 1024;
  unsigned short* lB1 = lB0 + 512;

  f32x4 acc[4][4];
  #pragma unroll
  for (int i = 0; i < 4; ++i)
    #pragma unroll
    for (int j = 0; j < 4; ++j) acc[i][j] = (f32x4)0.f;

  int frow = lane & 15, fk = (lane >> 4) * 8;

  for (int k0 = 0; k0 < K; k0 += 32) {
    __syncthreads();   // all waves done reading previous tile
    __builtin_amdgcn_global_load_lds((gv_t*)(gA0 + k0), (lv_t*)lA0, 16, 0, 0);
    __builtin_amdgcn_global_load_lds((gv_t*)(gA1 + k0), (lv_t*)lA1, 16, 0, 0);
    __builtin_amdgcn_global_load_lds((gv_t*)(gB0 + k0), (lv_t*)lB0, 16, 0, 0);
    __builtin_amdgcn_global_load_lds((gv_t*)(gB1 + k0), (lv_t*)lB1, 16, 0, 0);
    __syncthreads();   // compiler drains vmcnt before s_barrier -> tiles ready

    s16x8 af[4], bfr[4];
    #pragma unroll
    for (int i = 0; i < 4; ++i)
      af[i] = *(const s16x8*)&lgA[(wr * 64 + i * 16 + frow) * 32 + fk];
    #pragma unroll
    for (int j = 0; j < 4; ++j)
      bfr[j] = *(const s16x8*)&lgB[(wc * 64 + j * 16 + frow) * 32 + fk];
    #pragma unroll
    for (int i = 0; i < 4; ++i)
      #pragma unroll
      for (int j = 0; j < 4; ++j)
        acc[i][j] = __builtin_amdgcn_mfma_f32_16x16x32_bf16(af[i], bfr[j], acc[i][j], 0, 0, 0);
  }

  // epilogue: C/D layout col=lane&15, row=(lane>>4)*4+reg
  float bv[4];
  #pragma unroll
  for (int j = 0; j < 4; ++j) bv[j] = bias[n0 + wc * 64 + j * 16 + (lane & 15)];
  int rbase = m0 + wr * 64 + (lane >> 4) * 4;
  int cbase = n0 + wc * 64 + (lane & 15);
  #pragma unroll
  for (int i = 0; i < 4; ++i)
    #pragma unroll
    for (int r = 0; r < 4; ++r) {
      int m = rbase + i * 16 + r;
      if (m < Mw) {
        #pragma unroll
        for (int j = 0; j < 4; ++j) {
          float v = acc[i][j][r] + bv[j];
          if (ACT) v = fmaxf(v, 0.f);
          if (OBF) Cb[(size_t)m * ldc + cbase + j * 16] = f2bf(v);
          else     Cf[(size_t)m * ldc + cbase + j * 16] = v;
        }
      }
    }
}

// ---------------------------------------------------------------------------
// Flash attention, bf16 qkv input, fp32 math, bf16 output.
// qkv rows (B*T) x 3072: q [0,1024), k [1024,2048), v [2048,3072).
// ---------------------------------------------------------------------------
template <bool MASKED>
__global__ __launch_bounds__(256) void attn_kernel(
    const unsigned short* __restrict__ qkv,
    unsigned short* __restrict__ out) {
  __shared__ float Qs[32][68];
  __shared__ float Ks[64][68];
  __shared__ float Vs[64][68];
  __shared__ float Ps[32][68];
  int bh = blockIdx.y;
  int b = bh >> 4, h = bh & 15;
  int q0 = blockIdx.x * 32;
  int tid = threadIdx.x;
  int ql = tid >> 3;   // 0..31
  int cl = tid & 7;    // 0..7

  // load Q tile (32 x 64): one u16x8 per thread
  {
    int r = tid >> 3;
    int c = (tid & 7) * 8;
    int qr = q0 + r;
    if (qr >= T_) qr = T_ - 1;
    const unsigned short* qb =
        qkv + (size_t)(b * T_ + qr) * 3072 + h * 64 + c;
    u16x8 u = *(const u16x8*)qb;
    #pragma unroll
    for (int j = 0; j < 8; ++j) Qs[r][c + j] = bf2f(u[j]);
  }

  float m = -INFINITY, l = 0.f;
  float o[8] = {};
  int qmax = q0 + 31;

  for (int k0 = 0; k0 < T_; k0 += 64) {
    if (MASKED && k0 > qmax && k0 >= PREFIX_) break;
    __syncthreads();
    {
      int r = tid >> 2, c8 = (tid & 3) * 8;
      int kr = k0 + r;
      bool ok = kr < T_;
      const unsigned short* kb =
          qkv + (size_t)(b * T_ + (ok ? kr : 0)) * 3072 + 1024 + h * 64;
      #pragma unroll
      for (int half = 0; half < 2; ++half) {
        int col = c8 + half * 32;
        u16x8 ku, vu;
        if (ok) {
          ku = *(const u16x8*)(kb + col);
          vu = *(const u16x8*)(kb + 1024 + col);
        } else {
          #pragma unroll
          for (int j = 0; j < 8; ++j) { ku[j] = 0; vu[j] = 0; }
        }
        #pragma unroll
        for (int j = 0; j < 8; ++j) {
          Ks[r][col + j] = bf2f(ku[j]);
          Vs[r][col + j] = bf2f(vu[j]);
        }
      }
    }
    __syncthreads();

    float s[8];
    #pragma unroll
    for (int j = 0; j < 8; ++j) s[j] = 0.f;
    #pragma unroll 4
    for (int k4 = 0; k4 < 16; ++k4) {
      float4 q4 = *(const float4*)&Qs[ql][k4 * 4];
      #pragma unroll
      for (int j = 0; j < 8; ++j) {
        float4 kk4 = *(const float4*)&Ks[cl + 8 * j][k4 * 4];
        s[j] += q4.x * kk4.x + q4.y * kk4.y + q4.z * kk4.z + q4.w * kk4.w;
      }
    }

    int q = q0 + ql;
    float tm = -INFINITY;
    #pragma unroll
    for (int j = 0; j < 8; ++j) {
      int kg = k0 + cl + 8 * j;
      float sv = s[j] * 0.125f;
      bool bad = (kg >= T_) || (MASKED && kg > q && kg >= PREFIX_);
      sv = bad ? -INFINITY : sv;
      s[j] = sv;
      tm = fmaxf(tm, sv);
    }
    tm = fmaxf(tm, __shfl_xor(tm, 1));
    tm = fmaxf(tm, __shfl_xor(tm, 2));
    tm = fmaxf(tm, __shfl_xor(tm, 4));

    float mn = fmaxf(m, tm);
    float alpha = __expf(m - mn);
    float p[8], psum = 0.f;
    #pragma unroll
    for (int j = 0; j < 8; ++j) {
      p[j] = __expf(s[j] - mn);
      psum += p[j];
    }
    psum += __shfl_xor(psum, 1);
    psum += __shfl_xor(psum, 2);
    psum += __shfl_xor(psum, 4);
    l = l * alpha + psum;
    m = mn;
    #pragma unroll
    for (int j = 0; j < 8; ++j) o[j] *= alpha;
    #pragma unroll
    for (int j = 0; j < 8; ++j) Ps[ql][cl + 8 * j] = p[j];
    __syncthreads();

    for (int k = 0; k < 64; ++k) {
      float pvv = Ps[ql][k];
      #pragma unroll
      for (int j = 0; j < 8; ++j) o[j] += pvv * Vs[k][cl + 8 * j];
    }
  }

  float inv = 1.f / l;
  int q = q0 + ql;
  if (q < T_) {
    unsigned short* ob = out + (size_t)(b * T_ + q) * D_ + h * 64;
    #pragma unroll
    for (int j = 0; j < 8; ++j) ob[cl + 8 * j] = f2bf(o[j] * inv);
  }
}

// ---------------------------------------------------------------------------
// x = LayerNorm(x + r) * w + b ; writes fp32 x and bf16 shadow xb.
// ---------------------------------------------------------------------------
__global__ __launch_bounds__(256) void ln_res_kernel(
    float* __restrict__ x, const float* __restrict__ r,
    const float* __restrict__ w, const float* __restrict__ b,
    unsigned short* __restrict__ xb) {
  __shared__ float red[4];
  int row = blockIdx.x, tid = threadIdx.x;
  size_t off = (size_t)row * D_ + tid * 4;
  float4 xv = *(float4*)&x[off];
  float4 rv = *(const float4*)&r[off];
  float v0 = xv.x + rv.x, v1 = xv.y + rv.y, v2 = xv.z + rv.z, v3 = xv.w + rv.w;

  float s = v0 + v1 + v2 + v3;
  #pragma unroll
  for (int o = 1; o < 64; o <<= 1) s += __shfl_xor(s, o);
  if ((tid & 63) == 0) red[tid >> 6] = s;
  __syncthreads();
  float mu = (red[0] + red[1] + red[2] + red[3]) * (1.f / 1024.f);
  __syncthreads();

  float d0 = v0 - mu, d1 = v1 - mu, d2 = v2 - mu, d3 = v3 - mu;
  float ss = d0 * d0 + d1 * d1 + d2 * d2 + d3 * d3;
  #pragma unroll
  for (int o = 1; o < 64; o <<= 1) ss += __shfl_xor(ss, o);
  if ((tid & 63) == 0) red[tid >> 6] = ss;
  __syncthreads();
  float var = (red[0] + red[1] + red[2] + red[3]) * (1.f / 1024.f);
  float rs = rsqrtf(var + 1e-5f);

  float4 wv = *(const float4*)&w[tid * 4];
  float4 bv = *(const float4*)&b[tid * 4];
  float o0 = d0 * rs * wv.x + bv.x, o1 = d1 * rs * wv.y + bv.y;
  float o2 = d2 * rs * wv.z + bv.z, o3 = d3 * rs * wv.w + bv.w;
  *(float4*)&x[off] = make_float4(o0, o1, o2, o3);
  unsigned long long pk = (unsigned long long)f2bf(o0)
      | ((unsigned long long)f2bf(o1) << 16)
      | ((unsigned long long)f2bf(o2) << 32)
      | ((unsigned long long)f2bf(o3) << 48);
  *(unsigned long long*)&xb[off] = pk;
}

// ---------------------------------------------------------------------------
static inline void launch_gemm(const unsigned short* A, int lda,
                               const unsigned short* W, int ldw,
                               const float* bias, float* Cf, unsigned short* Cb,
                               int ldc, int Mw, int N, int K, int act,
                               hipStream_t s) {
  dim3 g(N / 128, M_PAD / 128);
  if (act) {
    if (Cb) gemm_bf16<1, 1><<<g, 256, 0, s>>>(A, lda, W, ldw, bias, Cf, Cb, ldc, Mw, K);
    else    gemm_bf16<1, 0><<<g, 256, 0, s>>>(A, lda, W, ldw, bias, Cf, Cb, ldc, Mw, K);
  } else {
    if (Cb) gemm_bf16<0, 1><<<g, 256, 0, s>>>(A, lda, W, ldw, bias, Cf, Cb, ldc, Mw, K);
    else    gemm_bf16<0, 0><<<g, 256, 0, s>>>(A, lda, W, ldw, bias, Cf, Cb, ldc, Mw, K);
  }
}

extern "C" void kernel_launch(void* const* d_in, const int* in_sizes, int n_in,
                              void* d_out, int out_size, void* d_ws, size_t ws_size,
                              hipStream_t stream) {
  const int* text       = (const int*)d_in[0];
  const int* audio      = (const int*)d_in[1];
  const int* enrolled   = (const int*)d_in[2];
  const int* tl_b       = (const int*)d_in[3];
  const int* al_b       = (const int*)d_in[4];
  const float* text_emb = (const float*)d_in[5];
  const float* audio_emb= (const float*)d_in[6];
  const float* sa_in_w  = (const float*)d_in[7];
  const float* sa_in_b  = (const float*)d_in[8];
  const float* sa_out_w = (const float*)d_in[9];
  const float* sa_out_b = (const float*)d_in[10];
  const float* ca_in_w  = (const float*)d_in[11];
  const float* ca_in_b  = (const float*)d_in[12];
  const float* ca_out_w = (const float*)d_in[13];
  const float* ca_out_b = (const float*)d_in[14];
  const float* ff1_w    = (const float*)d_in[15];
  const float* ff1_b    = (const float*)d_in[16];
  const float* ff2_w    = (const float*)d_in[17];
  const float* ff2_b    = (const float*)d_in[18];
  const float* ln1_w    = (const float*)d_in[19];
  const float* ln1_b    = (const float*)d_in[20];
  const float* ln2_w    = (const float*)d_in[21];
  const float* ln2_b    = (const float*)d_in[22];
  const float* ln3_w    = (const float*)d_in[23];
  const float* ln3_b    = (const float*)d_in[24];
  const float* out_w    = (const float*)d_in[25];
  const float* out_b    = (const float*)d_in[26];

  char* p = (char*)d_ws;
  float* xf = (float*)p;            p += (size_t)M_PAD * D_ * 4;
  float* tmp = (float*)p;           p += (size_t)M_PAD * D_ * 4;
  unsigned short* xb = (unsigned short*)p;    p += (size_t)M_PAD * D_ * 2;
  unsigned short* memb = (unsigned short*)p;  p += (size_t)M_PAD * D_ * 2;
  unsigned short* qkv = (unsigned short*)p;   p += (size_t)M_PAD * FF_ * 2;  // qkv / ffn-hidden
  unsigned short* attnb = (unsigned short*)p; p += (size_t)M_PAD * D_ * 2;
  unsigned short* wbuf = (unsigned short*)p;  p += (size_t)16777216 * 2;
  unsigned short* outwb = (unsigned short*)p; p += (size_t)1048576 * 2;

  unsigned short* w_sa_qkv = wbuf;
  unsigned short* w_sa_o   = wbuf + 3145728;
  unsigned short* w_ca_qkv = wbuf + 4194304;
  unsigned short* w_ca_o   = wbuf + 7340032;
  unsigned short* w_ff1    = wbuf + 8388608;
  unsigned short* w_ff2    = wbuf + 12582912;

  embed_kernel<<<M_PAD, 256, 0, stream>>>(text, audio, enrolled, tl_b, al_b,
                                          text_emb, audio_emb, xf, xb, memb, attnb);
  cvt_kernel<<<512, 256, 0, stream>>>(out_w, outwb, 131072);

  for (int l = 0; l < L_; ++l) {
    const float* sa_in_w_l  = sa_in_w  + (size_t)l * 3 * D_ * D_;
    const float* sa_in_b_l  = sa_in_b  + (size_t)l * 3 * D_;
    const float* sa_out_w_l = sa_out_w + (size_t)l * D_ * D_;
    const float* sa_out_b_l = sa_out_b + (size_t)l * D_;
    const float* ca_in_w_l  = ca_in_w  + (size_t)l * 3 * D_ * D_;
    const float* ca_in_b_l  = ca_in_b  + (size_t)l * 3 * D_;
    const float* ca_out_w_l = ca_out_w + (size_t)l * D_ * D_;
    const float* ca_out_b_l = ca_out_b + (size_t)l * D_;
    const float* ff1_w_l    = ff1_w    + (size_t)l * FF_ * D_;
    const float* ff1_b_l    = ff1_b    + (size_t)l * FF_;
    const float* ff2_w_l    = ff2_w    + (size_t)l * D_ * FF_;
    const float* ff2_b_l    = ff2_b    + (size_t)l * FF_ / FF_ * D_;  // l * D_

    cvt_layer_kernel<<<8192, 256, 0, stream>>>(sa_in_w_l, sa_out_w_l, ca_in_w_l,
                                               ca_out_w_l, ff1_w_l, ff2_w_l, wbuf);

    // ---- self attention ----
    launch_gemm(xb, D_, w_sa_qkv, D_, sa_in_b_l, nullptr, qkv, 3 * D_,
                M_PAD, 3 * D_, D_, 0, stream);
    attn_kernel<true><<<dim3(28, B_ * H_), 256, 0, stream>>>(qkv, attnb);
    launch_gemm(attnb, D_, w_sa_o, D_, sa_out_b_l, tmp, nullptr, D_,
                M_PAD, D_, D_, 0, stream);
    ln_res_kernel<<<M_TOK, 256, 0, stream>>>(xf, tmp, ln1_w + l * D_, ln1_b + l * D_, xb);

    // ---- cross attention ----
    launch_gemm(xb, D_, w_ca_qkv, D_, ca_in_b_l, nullptr, qkv, 3 * D_,
                M_PAD, D_, D_, 0, stream);                              // q
    launch_gemm(memb, D_, w_ca_qkv + (size_t)D_ * D_, D_, ca_in_b_l + D_,
                nullptr, qkv + D_, 3 * D_, M_PAD, 2 * D_, D_, 0, stream); // k,v
    attn_kernel<false><<<dim3(28, B_ * H_), 256, 0, stream>>>(qkv, attnb);
    launch_gemm(attnb, D_, w_ca_o, D_, ca_out_b_l, tmp, nullptr, D_,
                M_PAD, D_, D_, 0, stream);
    ln_res_kernel<<<M_TOK, 256, 0, stream>>>(xf, tmp, ln2_w + l * D_, ln2_b + l * D_, xb);

    // ---- feed forward ----
    launch_gemm(xb, D_, w_ff1, D_, ff1_b_l, nullptr, qkv, FF_,
                M_PAD, FF_, D_, 1, stream);
    launch_gemm(qkv, FF_, w_ff2, FF_, ff2_b_l, tmp, nullptr, D_,
                M_PAD, D_, FF_, 0, stream);
    ln_res_kernel<<<M_TOK, 256, 0, stream>>>(xf, tmp, ln3_w + l * D_, ln3_b + l * D_, xb);
  }

  // final projection -> d_out (fp32), only real rows
  launch_gemm(xb, D_, outwb, D_, out_b, (float*)d_out, nullptr, D_,
              M_TOK, D_, D_, 0, stream);
}

// Round 3
// 2702.083 us; speedup vs baseline: 5.5986x; 2.3345x over previous
//
#include <hip/hip_runtime.h>
#include <hip/hip_bf16.h>

#define B_      4
#define TT_     128
#define TA_     512
#define TE_     225
#define T_      865
#define D_      1024
#define H_      16
#define FF_     4096
#define L_      6
#define PREFIX_ 640
#define M_TOK   (B_ * T_)   // 3460
#define M_PAD   3584        // 28 * 128

typedef __attribute__((ext_vector_type(8))) short          s16x8;
typedef __attribute__((ext_vector_type(4))) float          f32x4;
typedef __attribute__((ext_vector_type(8))) unsigned short u16x8;

typedef __attribute__((address_space(1))) const void gv_t;
typedef __attribute__((address_space(3))) void       lv_t;

__device__ __forceinline__ float bf2f(unsigned short u) {
  union { unsigned int i; float f; } c; c.i = ((unsigned int)u) << 16; return c.f;
}
__device__ __forceinline__ unsigned short f2bf(float f) {
  union { __hip_bfloat16 h; unsigned short u; } c; c.h = __float2bfloat16(f); return c.u;
}

// ---------------------------------------------------------------------------
// Embedding + pack + PE. Grid = M_PAD rows; padded rows zero the bf16 bufs.
// ---------------------------------------------------------------------------
__global__ __launch_bounds__(256) void embed_kernel(
    const int* __restrict__ text, const int* __restrict__ audio,
    const int* __restrict__ enrolled, const int* __restrict__ tl_b,
    const int* __restrict__ al_b, const float* __restrict__ text_emb,
    const float* __restrict__ audio_emb,
    float* __restrict__ xf, unsigned short* __restrict__ xb,
    unsigned short* __restrict__ memb, unsigned short* __restrict__ attnb) {
  int row = blockIdx.x;
  int d0 = threadIdx.x * 4;
  size_t off = (size_t)row * D_ + d0;
  if (row >= M_TOK) {
    *(unsigned long long*)&xb[off]    = 0ull;
    *(unsigned long long*)&memb[off]  = 0ull;
    *(unsigned long long*)&attnb[off] = 0ull;
    return;
  }
  int b = row / T_, pos = row - b * T_;
  int tl = tl_b[b], al = al_b[b];
  const float* emb = nullptr;
  int p = 0;
  if (pos < tl) {
    emb = text_emb + (size_t)text[b * TT_ + pos] * D_;
    p = pos;
  } else if (pos < tl + al) {
    emb = audio_emb + (size_t)audio[b * TA_ + (pos - tl)] * D_;
    p = pos - tl;
  } else if (pos < tl + al + TE_) {
    emb = audio_emb + (size_t)enrolled[b * TE_ + (pos - tl - al)] * D_;
    p = pos - tl - al;
  }
  float4 v;
  float* pv = (float*)&v;
  if (emb) {
    const float c = -9.2103403719761836f / (float)D_;  // -ln(10000)/D
    #pragma unroll
    for (int e = 0; e < 4; ++e) {
      int d = d0 + e;
      int i = d >> 1;
      float freq = expf(c * (float)(2 * i));
      float arg = (float)p * freq;
      float pe = (d & 1) ? cosf(arg) : sinf(arg);
      pv[e] = emb[d] + pe;
    }
  } else {
    v = make_float4(0.f, 0.f, 0.f, 0.f);
  }
  *(float4*)&xf[off] = v;
  unsigned long long pk = (unsigned long long)f2bf(pv[0])
      | ((unsigned long long)f2bf(pv[1]) << 16)
      | ((unsigned long long)f2bf(pv[2]) << 32)
      | ((unsigned long long)f2bf(pv[3]) << 48);
  *(unsigned long long*)&xb[off]   = pk;
  *(unsigned long long*)&memb[off] = pk;
}

// ---------------------------------------------------------------------------
// fp32 -> bf16 converters (weights). 8 elems / thread.
// ---------------------------------------------------------------------------
__global__ __launch_bounds__(256) void cvt_kernel(
    const float* __restrict__ in, unsigned short* __restrict__ out, int n8) {
  int i = blockIdx.x * 256 + threadIdx.x;
  if (i >= n8) return;
  const float4* pp = (const float4*)in + (size_t)i * 2;
  float4 a = pp[0], bq = pp[1];
  u16x8 o;
  o[0] = f2bf(a.x);  o[1] = f2bf(a.y);  o[2] = f2bf(a.z);  o[3] = f2bf(a.w);
  o[4] = f2bf(bq.x); o[5] = f2bf(bq.y); o[6] = f2bf(bq.z); o[7] = f2bf(bq.w);
  *(u16x8*)(out + (size_t)i * 8) = o;
}

// All 6 weight matrices of one layer -> wbuf (16,777,216 elems total).
__global__ __launch_bounds__(256) void cvt_layer_kernel(
    const float* __restrict__ s0, const float* __restrict__ s1,
    const float* __restrict__ s2, const float* __restrict__ s3,
    const float* __restrict__ s4, const float* __restrict__ s5,
    unsigned short* __restrict__ dst) {
  size_t e = ((size_t)blockIdx.x * 256 + threadIdx.x) * 8;
  if (e >= 16777216u) return;
  const float* src; size_t off;
  if      (e <  3145728u) { src = s0; off = e; }
  else if (e <  4194304u) { src = s1; off = e -  3145728u; }
  else if (e <  7340032u) { src = s2; off = e -  4194304u; }
  else if (e <  8388608u) { src = s3; off = e -  7340032u; }
  else if (e < 12582912u) { src = s4; off = e -  8388608u; }
  else                    { src = s5; off = e - 12582912u; }
  const float4* pp = (const float4*)(src + off);
  float4 a = pp[0], bq = pp[1];
  u16x8 o;
  o[0] = f2bf(a.x);  o[1] = f2bf(a.y);  o[2] = f2bf(a.z);  o[3] = f2bf(a.w);
  o[4] = f2bf(bq.x); o[5] = f2bf(bq.y); o[6] = f2bf(bq.z); o[7] = f2bf(bq.w);
  *(u16x8*)(dst + e) = o;
}

// ---------------------------------------------------------------------------
// bf16 MFMA GEMM (m97 structure): C[M,N] = A[M,K] @ W[N,K]^T + bias.
// ---------------------------------------------------------------------------
template <int ACT, int OBF>
__global__ __launch_bounds__(256) void gemm_bf16(
    const unsigned short* __restrict__ A, int lda,
    const unsigned short* __restrict__ W, int ldw,
    const float* __restrict__ bias,
    float* __restrict__ Cf, unsigned short* __restrict__ Cb, int ldc,
    int Mw, int K) {
  __shared__ unsigned short lgA[128 * 32];   // [row][k] row-major
  __shared__ unsigned short lgB[128 * 32];
  int tid = threadIdx.x;
  int lane = tid & 63, wid = tid >> 6;
  int m0 = blockIdx.y * 128, n0 = blockIdx.x * 128;
  int wr = wid >> 1, wc = wid & 1;

  int lrow = lane >> 2;          // 0..15 within 16-row chunk
  int lk   = (lane & 3) * 8;     // k element offset
  const unsigned short* gA0 = A + (size_t)(m0 + wid * 32 + lrow) * lda + lk;
  const unsigned short* gA1 = gA0 + (size_t)16 * lda;
  const unsigned short* gB0 = W + (size_t)(n0 + wid * 32 + lrow) * ldw + lk;
  const unsigned short* gB1 = gB0 + (size_t)16 * ldw;
  unsigned short* lA0 = lgA + wid * 1024;        // wave-uniform bases
  unsigned short* lA1 = lA0 + 512;
  unsigned short* lB0 = lgB + wid * 1024;
  unsigned short* lB1 = lB0 + 512;

  f32x4 acc[4][4];
  #pragma unroll
  for (int i = 0; i < 4; ++i)
    #pragma unroll
    for (int j = 0; j < 4; ++j) acc[i][j] = (f32x4)0.f;

  int frow = lane & 15, fk = (lane >> 4) * 8;

  for (int k0 = 0; k0 < K; k0 += 32) {
    __syncthreads();
    __builtin_amdgcn_global_load_lds((gv_t*)(gA0 + k0), (lv_t*)lA0, 16, 0, 0);
    __builtin_amdgcn_global_load_lds((gv_t*)(gA1 + k0), (lv_t*)lA1, 16, 0, 0);
    __builtin_amdgcn_global_load_lds((gv_t*)(gB0 + k0), (lv_t*)lB0, 16, 0, 0);
    __builtin_amdgcn_global_load_lds((gv_t*)(gB1 + k0), (lv_t*)lB1, 16, 0, 0);
    __syncthreads();

    s16x8 af[4], bfr[4];
    #pragma unroll
    for (int i = 0; i < 4; ++i)
      af[i] = *(const s16x8*)&lgA[(wr * 64 + i * 16 + frow) * 32 + fk];
    #pragma unroll
    for (int j = 0; j < 4; ++j)
      bfr[j] = *(const s16x8*)&lgB[(wc * 64 + j * 16 + frow) * 32 + fk];
    #pragma unroll
    for (int i = 0; i < 4; ++i)
      #pragma unroll
      for (int j = 0; j < 4; ++j)
        acc[i][j] = __builtin_amdgcn_mfma_f32_16x16x32_bf16(af[i], bfr[j], acc[i][j], 0, 0, 0);
  }

  float bv[4];
  #pragma unroll
  for (int j = 0; j < 4; ++j) bv[j] = bias[n0 + wc * 64 + j * 16 + (lane & 15)];
  int rbase = m0 + wr * 64 + (lane >> 4) * 4;
  int cbase = n0 + wc * 64 + (lane & 15);
  #pragma unroll
  for (int i = 0; i < 4; ++i)
    #pragma unroll
    for (int r = 0; r < 4; ++r) {
      int m = rbase + i * 16 + r;
      if (m < Mw) {
        #pragma unroll
        for (int j = 0; j < 4; ++j) {
          float v = acc[i][j][r] + bv[j];
          if (ACT) v = fmaxf(v, 0.f);
          if (OBF) Cb[(size_t)m * ldc + cbase + j * 16] = f2bf(v);
          else     Cf[(size_t)m * ldc + cbase + j * 16] = v;
        }
      }
    }
}

// ---------------------------------------------------------------------------
// MFMA flash attention. qkv rows (B*T) x 3072: q [0,1024), k [1024,2048),
// v [2048,3072). Grid: (14, B*H), 256 threads (4 waves x 16 q-rows).
// K staged via global_load_lds with XOR-swizzled SOURCE (rule #21);
// V reg-staged + transposed to Vt[d][key]; P via per-wave swizzled LDS.
// ---------------------------------------------------------------------------
template <bool MASKED>
__global__ __launch_bounds__(256) void attn_mfma(
    const unsigned short* __restrict__ qkv,
    unsigned short* __restrict__ out) {
  __shared__ unsigned short KsL[64 * 64];      // [key][d], 16B-groups swizzled
  __shared__ unsigned short VtL[64 * 72];      // [d][key], pad 72
  __shared__ unsigned short PsL[4][16 * 64];   // per-wave P[qrow][key], swizzled
  int tid = threadIdx.x;
  int lane = tid & 63, wid = tid >> 6;
  int b = blockIdx.y >> 4, h = blockIdx.y & 15;
  int q0 = blockIdx.x * 64;
  int r16 = lane & 15, g4 = lane >> 4;

  // Q fragments: A-layout row=lane&15, k=(lane>>4)*8+j
  int qrow = q0 + wid * 16 + r16;
  if (qrow >= T_) qrow = T_ - 1;
  const unsigned short* qbase =
      qkv + (size_t)(b * T_ + qrow) * 3072 + h * 64 + g4 * 8;
  s16x8 qf0 = *(const s16x8*)qbase;
  s16x8 qf1 = *(const s16x8*)(qbase + 32);

  float m_[4], l_[4];
  f32x4 o_[4];
  #pragma unroll
  for (int rg = 0; rg < 4; ++rg) { m_[rg] = -INFINITY; l_[rg] = 0.f; }
  #pragma unroll
  for (int dj = 0; dj < 4; ++dj) o_[dj] = (f32x4)0.f;

  const int nt = MASKED ? max(10, (int)blockIdx.x + 1) : 14;

  for (int t = 0; t < nt; ++t) {
    int k0 = t * 64;
    __syncthreads();   // prior tile's LDS reads complete

    // --- stage K (wave wid: keys wid*16..+16), swizzled source ---
    #pragma unroll
    for (int c = 0; c < 2; ++c) {
      int row = wid * 16 + c * 8 + (lane >> 3);
      int kr = k0 + row; if (kr >= T_) kr = T_ - 1;
      int grp = (lane & 7) ^ (row & 7);
      const unsigned short* src =
          qkv + (size_t)(b * T_ + kr) * 3072 + 1024 + h * 64 + grp * 8;
      __builtin_amdgcn_global_load_lds((gv_t*)src,
          (lv_t*)&KsL[(wid * 16 + c * 8) * 64], 16, 0, 0);
    }
    // --- stage V transposed: wave wid owns d-rows wid*16..+16, key = lane ---
    {
      int vkr = k0 + lane; if (vkr >= T_) vkr = T_ - 1;
      const unsigned short* vsrc =
          qkv + (size_t)(b * T_ + vkr) * 3072 + 2048 + h * 64 + wid * 16;
      u16x8 v0 = *(const u16x8*)vsrc;
      u16x8 v1 = *(const u16x8*)(vsrc + 8);
      #pragma unroll
      for (int jj = 0; jj < 8; ++jj) {
        VtL[(wid * 16 + jj) * 72 + lane]     = v0[jj];
        VtL[(wid * 16 + 8 + jj) * 72 + lane] = v1[jj];
      }
    }
    __syncthreads();   // K/V tiles ready

    // --- S = Q K^T : 8 MFMAs ---
    f32x4 sj[4];
    #pragma unroll
    for (int j = 0; j < 4; ++j) sj[j] = (f32x4)0.f;
    __builtin_amdgcn_s_setprio(1);
    #pragma unroll
    for (int j = 0; j < 4; ++j) {
      int krow = j * 16 + r16;
      s16x8 kf0 = *(const s16x8*)&KsL[krow * 64 + ((g4 ^ (krow & 7)) * 8)];
      s16x8 kf1 = *(const s16x8*)&KsL[krow * 64 + (((4 + g4) ^ (krow & 7)) * 8)];
      sj[j] = __builtin_amdgcn_mfma_f32_16x16x32_bf16(qf0, kf0, sj[j], 0, 0, 0);
      sj[j] = __builtin_amdgcn_mfma_f32_16x16x32_bf16(qf1, kf1, sj[j], 0, 0, 0);
    }
    __builtin_amdgcn_s_setprio(0);

    // --- online softmax (rows: q = q0 + wid*16 + g4*4 + reg) ---
    float alpha_[4];
    #pragma unroll
    for (int rg = 0; rg < 4; ++rg) {
      int qa = q0 + wid * 16 + g4 * 4 + rg;
      float pm = -INFINITY;
      #pragma unroll
      for (int j = 0; j < 4; ++j) {
        int kg = k0 + j * 16 + r16;
        float sv = sj[j][rg] * 0.125f;
        bool bad = (kg >= T_) || (MASKED && kg > qa && kg >= PREFIX_);
        sv = bad ? -INFINITY : sv;
        sj[j][rg] = sv;
        pm = fmaxf(pm, sv);
      }
      pm = fmaxf(pm, __shfl_xor(pm, 1));
      pm = fmaxf(pm, __shfl_xor(pm, 2));
      pm = fmaxf(pm, __shfl_xor(pm, 4));
      pm = fmaxf(pm, __shfl_xor(pm, 8));
      float mn = fmaxf(m_[rg], pm);
      float al = __expf(m_[rg] - mn);
      m_[rg] = mn;
      alpha_[rg] = al;
      int prow = g4 * 4 + rg;
      float ps = 0.f;
      #pragma unroll
      for (int j = 0; j < 4; ++j) {
        float pv = __expf(sj[j][rg] - mn);
        ps += pv;
        PsL[wid][prow * 64 + (((j * 2 + (r16 >> 3)) ^ (prow & 7)) * 8) + (r16 & 7)]
            = f2bf(pv);
      }
      ps += __shfl_xor(ps, 1);
      ps += __shfl_xor(ps, 2);
      ps += __shfl_xor(ps, 4);
      ps += __shfl_xor(ps, 8);
      l_[rg] = l_[rg] * al + ps;
    }
    #pragma unroll
    for (int dj = 0; dj < 4; ++dj)
      #pragma unroll
      for (int rg = 0; rg < 4; ++rg) o_[dj][rg] *= alpha_[rg];

    // --- O += P @ V : 8 MFMAs (A=P from PsL, B=Vt rows) ---
    __builtin_amdgcn_s_setprio(1);
    #pragma unroll
    for (int kk = 0; kk < 2; ++kk) {
      s16x8 pf = *(const s16x8*)
          &PsL[wid][r16 * 64 + (((kk * 4 + g4) ^ (r16 & 7)) * 8)];
      #pragma unroll
      for (int dj = 0; dj < 4; ++dj) {
        s16x8 vf = *(const s16x8*)
            &VtL[(dj * 16 + r16) * 72 + kk * 32 + g4 * 8];
        o_[dj] = __builtin_amdgcn_mfma_f32_16x16x32_bf16(pf, vf, o_[dj], 0, 0, 0);
      }
    }
    __builtin_amdgcn_s_setprio(0);
  }

  // --- store ---
  #pragma unroll
  for (int rg = 0; rg < 4; ++rg) {
    int qa = q0 + wid * 16 + g4 * 4 + rg;
    if (qa < T_) {
      float inv = 1.f / l_[rg];
      unsigned short* ob = out + (size_t)(b * T_ + qa) * D_ + h * 64;
      #pragma unroll
      for (int dj = 0; dj < 4; ++dj)
        ob[dj * 16 + r16] = f2bf(o_[dj][rg] * inv);
    }
  }
}

// ---------------------------------------------------------------------------
// x = LayerNorm(x + r) * w + b ; writes fp32 x and bf16 shadow xb.
// ---------------------------------------------------------------------------
__global__ __launch_bounds__(256) void ln_res_kernel(
    float* __restrict__ x, const float* __restrict__ r,
    const float* __restrict__ w, const float* __restrict__ b,
    unsigned short* __restrict__ xb) {
  __shared__ float red[4];
  int row = blockIdx.x, tid = threadIdx.x;
  size_t off = (size_t)row * D_ + tid * 4;
  float4 xv = *(float4*)&x[off];
  float4 rv = *(const float4*)&r[off];
  float v0 = xv.x + rv.x, v1 = xv.y + rv.y, v2 = xv.z + rv.z, v3 = xv.w + rv.w;

  float s = v0 + v1 + v2 + v3;
  #pragma unroll
  for (int o = 1; o < 64; o <<= 1) s += __shfl_xor(s, o);
  if ((tid & 63) == 0) red[tid >> 6] = s;
  __syncthreads();
  float mu = (red[0] + red[1] + red[2] + red[3]) * (1.f / 1024.f);
  __syncthreads();

  float d0 = v0 - mu, d1 = v1 - mu, d2 = v2 - mu, d3 = v3 - mu;
  float ss = d0 * d0 + d1 * d1 + d2 * d2 + d3 * d3;
  #pragma unroll
  for (int o = 1; o < 64; o <<= 1) ss += __shfl_xor(ss, o);
  if ((tid & 63) == 0) red[tid >> 6] = ss;
  __syncthreads();
  float var = (red[0] + red[1] + red[2] + red[3]) * (1.f / 1024.f);
  float rs = rsqrtf(var + 1e-5f);

  float4 wv = *(const float4*)&w[tid * 4];
  float4 bv = *(const float4*)&b[tid * 4];
  float o0 = d0 * rs * wv.x + bv.x, o1 = d1 * rs * wv.y + bv.y;
  float o2 = d2 * rs * wv.z + bv.z, o3 = d3 * rs * wv.w + bv.w;
  *(float4*)&x[off] = make_float4(o0, o1, o2, o3);
  unsigned long long pk = (unsigned long long)f2bf(o0)
      | ((unsigned long long)f2bf(o1) << 16)
      | ((unsigned long long)f2bf(o2) << 32)
      | ((unsigned long long)f2bf(o3) << 48);
  *(unsigned long long*)&xb[off] = pk;
}

// ---------------------------------------------------------------------------
static inline void launch_gemm(const unsigned short* A, int lda,
                               const unsigned short* W, int ldw,
                               const float* bias, float* Cf, unsigned short* Cb,
                               int ldc, int Mw, int N, int K, int act,
                               hipStream_t s) {
  dim3 g(N / 128, M_PAD / 128);
  if (act) {
    if (Cb) gemm_bf16<1, 1><<<g, 256, 0, s>>>(A, lda, W, ldw, bias, Cf, Cb, ldc, Mw, K);
    else    gemm_bf16<1, 0><<<g, 256, 0, s>>>(A, lda, W, ldw, bias, Cf, Cb, ldc, Mw, K);
  } else {
    if (Cb) gemm_bf16<0, 1><<<g, 256, 0, s>>>(A, lda, W, ldw, bias, Cf, Cb, ldc, Mw, K);
    else    gemm_bf16<0, 0><<<g, 256, 0, s>>>(A, lda, W, ldw, bias, Cf, Cb, ldc, Mw, K);
  }
}

extern "C" void kernel_launch(void* const* d_in, const int* in_sizes, int n_in,
                              void* d_out, int out_size, void* d_ws, size_t ws_size,
                              hipStream_t stream) {
  const int* text       = (const int*)d_in[0];
  const int* audio      = (const int*)d_in[1];
  const int* enrolled   = (const int*)d_in[2];
  const int* tl_b       = (const int*)d_in[3];
  const int* al_b       = (const int*)d_in[4];
  const float* text_emb = (const float*)d_in[5];
  const float* audio_emb= (const float*)d_in[6];
  const float* sa_in_w  = (const float*)d_in[7];
  const float* sa_in_b  = (const float*)d_in[8];
  const float* sa_out_w = (const float*)d_in[9];
  const float* sa_out_b = (const float*)d_in[10];
  const float* ca_in_w  = (const float*)d_in[11];
  const float* ca_in_b  = (const float*)d_in[12];
  const float* ca_out_w = (const float*)d_in[13];
  const float* ca_out_b = (const float*)d_in[14];
  const float* ff1_w    = (const float*)d_in[15];
  const float* ff1_b    = (const float*)d_in[16];
  const float* ff2_w    = (const float*)d_in[17];
  const float* ff2_b    = (const float*)d_in[18];
  const float* ln1_w    = (const float*)d_in[19];
  const float* ln1_b    = (const float*)d_in[20];
  const float* ln2_w    = (const float*)d_in[21];
  const float* ln2_b    = (const float*)d_in[22];
  const float* ln3_w    = (const float*)d_in[23];
  const float* ln3_b    = (const float*)d_in[24];
  const float* out_w    = (const float*)d_in[25];
  const float* out_b    = (const float*)d_in[26];

  char* p = (char*)d_ws;
  float* xf = (float*)p;            p += (size_t)M_PAD * D_ * 4;
  float* tmp = (float*)p;           p += (size_t)M_PAD * D_ * 4;
  unsigned short* xb = (unsigned short*)p;    p += (size_t)M_PAD * D_ * 2;
  unsigned short* memb = (unsigned short*)p;  p += (size_t)M_PAD * D_ * 2;
  unsigned short* qkv = (unsigned short*)p;   p += (size_t)M_PAD * FF_ * 2;
  unsigned short* attnb = (unsigned short*)p; p += (size_t)M_PAD * D_ * 2;
  unsigned short* wbuf = (unsigned short*)p;  p += (size_t)16777216 * 2;
  unsigned short* outwb = (unsigned short*)p; p += (size_t)1048576 * 2;

  unsigned short* w_sa_qkv = wbuf;
  unsigned short* w_sa_o   = wbuf + 3145728;
  unsigned short* w_ca_qkv = wbuf + 4194304;
  unsigned short* w_ca_o   = wbuf + 7340032;
  unsigned short* w_ff1    = wbuf + 8388608;
  unsigned short* w_ff2    = wbuf + 12582912;

  embed_kernel<<<M_PAD, 256, 0, stream>>>(text, audio, enrolled, tl_b, al_b,
                                          text_emb, audio_emb, xf, xb, memb, attnb);
  cvt_kernel<<<512, 256, 0, stream>>>(out_w, outwb, 131072);

  for (int l = 0; l < L_; ++l) {
    const float* sa_in_w_l  = sa_in_w  + (size_t)l * 3 * D_ * D_;
    const float* sa_in_b_l  = sa_in_b  + (size_t)l * 3 * D_;
    const float* sa_out_w_l = sa_out_w + (size_t)l * D_ * D_;
    const float* sa_out_b_l = sa_out_b + (size_t)l * D_;
    const float* ca_in_w_l  = ca_in_w  + (size_t)l * 3 * D_ * D_;
    const float* ca_in_b_l  = ca_in_b  + (size_t)l * 3 * D_;
    const float* ca_out_w_l = ca_out_w + (size_t)l * D_ * D_;
    const float* ca_out_b_l = ca_out_b + (size_t)l * D_;
    const float* ff1_w_l    = ff1_w    + (size_t)l * FF_ * D_;
    const float* ff1_b_l    = ff1_b    + (size_t)l * FF_;
    const float* ff2_w_l    = ff2_w    + (size_t)l * D_ * FF_;
    const float* ff2_b_l    = ff2_b    + (size_t)l * D_;

    cvt_layer_kernel<<<8192, 256, 0, stream>>>(sa_in_w_l, sa_out_w_l, ca_in_w_l,
                                               ca_out_w_l, ff1_w_l, ff2_w_l, wbuf);

    // ---- self attention ----
    launch_gemm(xb, D_, w_sa_qkv, D_, sa_in_b_l, nullptr, qkv, 3 * D_,
                M_PAD, 3 * D_, D_, 0, stream);
    attn_mfma<true><<<dim3(14, B_ * H_), 256, 0, stream>>>(qkv, attnb);
    launch_gemm(attnb, D_, w_sa_o, D_, sa_out_b_l, tmp, nullptr, D_,
                M_PAD, D_, D_, 0, stream);
    ln_res_kernel<<<M_TOK, 256, 0, stream>>>(xf, tmp, ln1_w + l * D_, ln1_b + l * D_, xb);

    // ---- cross attention ----
    launch_gemm(xb, D_, w_ca_qkv, D_, ca_in_b_l, nullptr, qkv, 3 * D_,
                M_PAD, D_, D_, 0, stream);                                // q
    launch_gemm(memb, D_, w_ca_qkv + (size_t)D_ * D_, D_, ca_in_b_l + D_,
                nullptr, qkv + D_, 3 * D_, M_PAD, 2 * D_, D_, 0, stream); // k,v
    attn_mfma<false><<<dim3(14, B_ * H_), 256, 0, stream>>>(qkv, attnb);
    launch_gemm(attnb, D_, w_ca_o, D_, ca_out_b_l, tmp, nullptr, D_,
                M_PAD, D_, D_, 0, stream);
    ln_res_kernel<<<M_TOK, 256, 0, stream>>>(xf, tmp, ln2_w + l * D_, ln2_b + l * D_, xb);

    // ---- feed forward ----
    launch_gemm(xb, D_, w_ff1, D_, ff1_b_l, nullptr, qkv, FF_,
                M_PAD, FF_, D_, 1, stream);
    launch_gemm(qkv, FF_, w_ff2, FF_, ff2_b_l, tmp, nullptr, D_,
                M_PAD, D_, FF_, 0, stream);
    ln_res_kernel<<<M_TOK, 256, 0, stream>>>(xf, tmp, ln3_w + l * D_, ln3_b + l * D_, xb);
  }

  // final projection -> d_out (fp32), only real rows
  launch_gemm(xb, D_, outwb, D_, out_b, (float*)d_out, nullptr, D_,
              M_TOK, D_, D_, 0, stream);
}

// Round 4
// 2288.282 us; speedup vs baseline: 6.6110x; 1.1808x over previous
//
#include <hip/hip_runtime.h>
#include <hip/hip_bf16.h>

#define B_      4
#define TT_     128
#define TA_     512
#define TE_     225
#define T_      865
#define D_      1024
#define H_      16
#define FF_     4096
#define L_      6
#define PREFIX_ 640
#define M_TOK   (B_ * T_)   // 3460
#define M_PAD   3584        // 28 * 128

typedef __attribute__((ext_vector_type(8))) short          s16x8;
typedef __attribute__((ext_vector_type(4))) float          f32x4;
typedef __attribute__((ext_vector_type(8))) unsigned short u16x8;

typedef __attribute__((address_space(1))) const void gv_t;
typedef __attribute__((address_space(3))) void       lv_t;

__device__ __forceinline__ float bf2f(unsigned short u) {
  union { unsigned int i; float f; } c; c.i = ((unsigned int)u) << 16; return c.f;
}
__device__ __forceinline__ unsigned short f2bf(float f) {
  union { __hip_bfloat16 h; unsigned short u; } c; c.h = __float2bfloat16(f); return c.u;
}

// ---------------------------------------------------------------------------
// Embedding + pack + PE. Grid = M_PAD rows; padded rows zero the bf16 bufs.
// ---------------------------------------------------------------------------
__global__ __launch_bounds__(256) void embed_kernel(
    const int* __restrict__ text, const int* __restrict__ audio,
    const int* __restrict__ enrolled, const int* __restrict__ tl_b,
    const int* __restrict__ al_b, const float* __restrict__ text_emb,
    const float* __restrict__ audio_emb,
    float* __restrict__ xf, unsigned short* __restrict__ xb,
    unsigned short* __restrict__ memb, unsigned short* __restrict__ attnb) {
  int row = blockIdx.x;
  int d0 = threadIdx.x * 4;
  size_t off = (size_t)row * D_ + d0;
  if (row >= M_TOK) {
    *(unsigned long long*)&xb[off]    = 0ull;
    *(unsigned long long*)&memb[off]  = 0ull;
    *(unsigned long long*)&attnb[off] = 0ull;
    return;
  }
  int b = row / T_, pos = row - b * T_;
  int tl = tl_b[b], al = al_b[b];
  const float* emb = nullptr;
  int p = 0;
  if (pos < tl) {
    emb = text_emb + (size_t)text[b * TT_ + pos] * D_;
    p = pos;
  } else if (pos < tl + al) {
    emb = audio_emb + (size_t)audio[b * TA_ + (pos - tl)] * D_;
    p = pos - tl;
  } else if (pos < tl + al + TE_) {
    emb = audio_emb + (size_t)enrolled[b * TE_ + (pos - tl - al)] * D_;
    p = pos - tl - al;
  }
  float4 v;
  float* pv = (float*)&v;
  if (emb) {
    const float c = -9.2103403719761836f / (float)D_;  // -ln(10000)/D
    #pragma unroll
    for (int e = 0; e < 4; ++e) {
      int d = d0 + e;
      int i = d >> 1;
      float freq = expf(c * (float)(2 * i));
      float arg = (float)p * freq;
      float pe = (d & 1) ? cosf(arg) : sinf(arg);
      pv[e] = emb[d] + pe;
    }
  } else {
    v = make_float4(0.f, 0.f, 0.f, 0.f);
  }
  *(float4*)&xf[off] = v;
  unsigned long long pk = (unsigned long long)f2bf(pv[0])
      | ((unsigned long long)f2bf(pv[1]) << 16)
      | ((unsigned long long)f2bf(pv[2]) << 32)
      | ((unsigned long long)f2bf(pv[3]) << 48);
  *(unsigned long long*)&xb[off]   = pk;
  *(unsigned long long*)&memb[off] = pk;
}

// ---------------------------------------------------------------------------
// fp32 -> bf16 converters (weights). 8 elems / thread.
// ---------------------------------------------------------------------------
__global__ __launch_bounds__(256) void cvt_kernel(
    const float* __restrict__ in, unsigned short* __restrict__ out, int n8) {
  int i = blockIdx.x * 256 + threadIdx.x;
  if (i >= n8) return;
  const float4* pp = (const float4*)in + (size_t)i * 2;
  float4 a = pp[0], bq = pp[1];
  u16x8 o;
  o[0] = f2bf(a.x);  o[1] = f2bf(a.y);  o[2] = f2bf(a.z);  o[3] = f2bf(a.w);
  o[4] = f2bf(bq.x); o[5] = f2bf(bq.y); o[6] = f2bf(bq.z); o[7] = f2bf(bq.w);
  *(u16x8*)(out + (size_t)i * 8) = o;
}

// All 6 weight matrices of one layer -> wbuf (16,777,216 elems total).
__global__ __launch_bounds__(256) void cvt_layer_kernel(
    const float* __restrict__ s0, const float* __restrict__ s1,
    const float* __restrict__ s2, const float* __restrict__ s3,
    const float* __restrict__ s4, const float* __restrict__ s5,
    unsigned short* __restrict__ dst) {
  size_t e = ((size_t)blockIdx.x * 256 + threadIdx.x) * 8;
  if (e >= 16777216u) return;
  const float* src; size_t off;
  if      (e <  3145728u) { src = s0; off = e; }
  else if (e <  4194304u) { src = s1; off = e -  3145728u; }
  else if (e <  7340032u) { src = s2; off = e -  4194304u; }
  else if (e <  8388608u) { src = s3; off = e -  7340032u; }
  else if (e < 12582912u) { src = s4; off = e -  8388608u; }
  else                    { src = s5; off = e - 12582912u; }
  const float4* pp = (const float4*)(src + off);
  float4 a = pp[0], bq = pp[1];
  u16x8 o;
  o[0] = f2bf(a.x);  o[1] = f2bf(a.y);  o[2] = f2bf(a.z);  o[3] = f2bf(a.w);
  o[4] = f2bf(bq.x); o[5] = f2bf(bq.y); o[6] = f2bf(bq.z); o[7] = f2bf(bq.w);
  *(u16x8*)(dst + e) = o;
}

// ---------------------------------------------------------------------------
// 2-phase pipelined bf16 MFMA GEMM: C[M,N] = A[M,K] @ W[N,K]^T + bias.
// Tile BM x BN (2x2 waves), BK=32, double-buffered LDS, prefetch-next,
// one barrier per K-step (its vmcnt(0) drain retires the prefetch).
// XCD-bijective block swizzle (m204). ACT: relu. OBF: bf16 output.
// ---------------------------------------------------------------------------
template <int BM, int BN, int ACT, int OBF>
__global__ __launch_bounds__(256) void gemm_bf16(
    const unsigned short* __restrict__ A, int lda,
    const unsigned short* __restrict__ W, int ldw,
    const float* __restrict__ bias,
    float* __restrict__ Cf, unsigned short* __restrict__ Cb, int ldc,
    int Mw, int K) {
  constexpr int WROWS = BM / 2, WCOLS = BN / 2;   // per-wave output tile
  constexpr int WM = WROWS / 16, WN = WCOLS / 16; // frag repeats
  constexpr int ACH = BM / 64, BCH = BN / 64;     // 16-row stage chunks / wave
  __shared__ unsigned short lgA[2][BM * 32];
  __shared__ unsigned short lgB[2][BN * 32];
  int tid = threadIdx.x, lane = tid & 63, wid = tid >> 6;

  // XCD-aware bijective swizzle: each XCD gets a contiguous tile range.
  int gx = gridDim.x;
  int nwg = gx * gridDim.y;
  int orig = blockIdx.y * gx + blockIdx.x;
  int q = nwg >> 3, r = nwg & 7;
  int xcd = orig & 7, loc = orig >> 3;
  int wg = (xcd < r ? xcd * (q + 1) : r * (q + 1) + (xcd - r) * q) + loc;
  int m0 = (wg / gx) * BM, n0 = (wg % gx) * BN;

  int wr = wid >> 1, wc = wid & 1;
  int lrow = lane >> 2, lk = (lane & 3) * 8;

  const unsigned short* gAp[ACH];
  const unsigned short* gBp[BCH];
  unsigned aoff[ACH], boff[BCH];
  #pragma unroll
  for (int c = 0; c < ACH; ++c) {
    int row0 = wid * (16 * ACH) + 16 * c;
    gAp[c] = A + (size_t)(m0 + row0 + lrow) * lda + lk;
    aoff[c] = row0 * 32;
  }
  #pragma unroll
  for (int c = 0; c < BCH; ++c) {
    int row0 = wid * (16 * BCH) + 16 * c;
    gBp[c] = W + (size_t)(n0 + row0 + lrow) * ldw + lk;
    boff[c] = row0 * 32;
  }

  f32x4 acc[WM][WN];
  #pragma unroll
  for (int i = 0; i < WM; ++i)
    #pragma unroll
    for (int j = 0; j < WN; ++j) acc[i][j] = (f32x4)0.f;

  int frow = lane & 15, fk = (lane >> 4) * 8;

  // prologue: stage K-step 0 into buf0
  #pragma unroll
  for (int c = 0; c < ACH; ++c)
    __builtin_amdgcn_global_load_lds((gv_t*)gAp[c], (lv_t*)&lgA[0][aoff[c]], 16, 0, 0);
  #pragma unroll
  for (int c = 0; c < BCH; ++c)
    __builtin_amdgcn_global_load_lds((gv_t*)gBp[c], (lv_t*)&lgB[0][boff[c]], 16, 0, 0);
  __syncthreads();   // vmcnt(0) drain -> buf0 ready

  int nt = K / 32;
  for (int t = 0; t < nt; ++t) {
    int cur = t & 1;
    if (t + 1 < nt) {   // issue prefetch for t+1 into the other buffer
      int k0 = (t + 1) * 32;
      #pragma unroll
      for (int c = 0; c < ACH; ++c)
        __builtin_amdgcn_global_load_lds((gv_t*)(gAp[c] + k0),
                                         (lv_t*)&lgA[cur ^ 1][aoff[c]], 16, 0, 0);
      #pragma unroll
      for (int c = 0; c < BCH; ++c)
        __builtin_amdgcn_global_load_lds((gv_t*)(gBp[c] + k0),
                                         (lv_t*)&lgB[cur ^ 1][boff[c]], 16, 0, 0);
    }
    s16x8 af[WM], bfr[WN];
    #pragma unroll
    for (int i = 0; i < WM; ++i)
      af[i] = *(const s16x8*)&lgA[cur][(wr * WROWS + i * 16 + frow) * 32 + fk];
    #pragma unroll
    for (int j = 0; j < WN; ++j)
      bfr[j] = *(const s16x8*)&lgB[cur][(wc * WCOLS + j * 16 + frow) * 32 + fk];
    __builtin_amdgcn_s_setprio(1);
    #pragma unroll
    for (int i = 0; i < WM; ++i)
      #pragma unroll
      for (int j = 0; j < WN; ++j)
        acc[i][j] = __builtin_amdgcn_mfma_f32_16x16x32_bf16(af[i], bfr[j], acc[i][j], 0, 0, 0);
    __builtin_amdgcn_s_setprio(0);
    __syncthreads();   // drains vmcnt (prefetch landed) + all reads of cur done
  }

  // epilogue: C/D layout col=lane&15, row=(lane>>4)*4+reg
  float bv[WN];
  #pragma unroll
  for (int j = 0; j < WN; ++j) bv[j] = bias[n0 + wc * WCOLS + j * 16 + (lane & 15)];
  int rbase = m0 + wr * WROWS + (lane >> 4) * 4;
  int cbase = n0 + wc * WCOLS + (lane & 15);
  #pragma unroll
  for (int i = 0; i < WM; ++i)
    #pragma unroll
    for (int rr = 0; rr < 4; ++rr) {
      int m = rbase + i * 16 + rr;
      if (m < Mw) {
        #pragma unroll
        for (int j = 0; j < WN; ++j) {
          float v = acc[i][j][rr] + bv[j];
          if (ACT) v = fmaxf(v, 0.f);
          if (OBF) Cb[(size_t)m * ldc + cbase + j * 16] = f2bf(v);
          else     Cf[(size_t)m * ldc + cbase + j * 16] = v;
        }
      }
    }
}

// ---------------------------------------------------------------------------
// MFMA flash attention (unchanged from round 3).
// ---------------------------------------------------------------------------
template <bool MASKED>
__global__ __launch_bounds__(256) void attn_mfma(
    const unsigned short* __restrict__ qkv,
    unsigned short* __restrict__ out) {
  __shared__ unsigned short KsL[64 * 64];      // [key][d], 16B-groups swizzled
  __shared__ unsigned short VtL[64 * 72];      // [d][key], pad 72
  __shared__ unsigned short PsL[4][16 * 64];   // per-wave P[qrow][key], swizzled
  int tid = threadIdx.x;
  int lane = tid & 63, wid = tid >> 6;
  int b = blockIdx.y >> 4, h = blockIdx.y & 15;
  int q0 = blockIdx.x * 64;
  int r16 = lane & 15, g4 = lane >> 4;

  int qrow = q0 + wid * 16 + r16;
  if (qrow >= T_) qrow = T_ - 1;
  const unsigned short* qbase =
      qkv + (size_t)(b * T_ + qrow) * 3072 + h * 64 + g4 * 8;
  s16x8 qf0 = *(const s16x8*)qbase;
  s16x8 qf1 = *(const s16x8*)(qbase + 32);

  float m_[4], l_[4];
  f32x4 o_[4];
  #pragma unroll
  for (int rg = 0; rg < 4; ++rg) { m_[rg] = -INFINITY; l_[rg] = 0.f; }
  #pragma unroll
  for (int dj = 0; dj < 4; ++dj) o_[dj] = (f32x4)0.f;

  const int nt = MASKED ? max(10, (int)blockIdx.x + 1) : 14;

  for (int t = 0; t < nt; ++t) {
    int k0 = t * 64;
    __syncthreads();

    #pragma unroll
    for (int c = 0; c < 2; ++c) {
      int row = wid * 16 + c * 8 + (lane >> 3);
      int kr = k0 + row; if (kr >= T_) kr = T_ - 1;
      int grp = (lane & 7) ^ (row & 7);
      const unsigned short* src =
          qkv + (size_t)(b * T_ + kr) * 3072 + 1024 + h * 64 + grp * 8;
      __builtin_amdgcn_global_load_lds((gv_t*)src,
          (lv_t*)&KsL[(wid * 16 + c * 8) * 64], 16, 0, 0);
    }
    {
      int vkr = k0 + lane; if (vkr >= T_) vkr = T_ - 1;
      const unsigned short* vsrc =
          qkv + (size_t)(b * T_ + vkr) * 3072 + 2048 + h * 64 + wid * 16;
      u16x8 v0 = *(const u16x8*)vsrc;
      u16x8 v1 = *(const u16x8*)(vsrc + 8);
      #pragma unroll
      for (int jj = 0; jj < 8; ++jj) {
        VtL[(wid * 16 + jj) * 72 + lane]     = v0[jj];
        VtL[(wid * 16 + 8 + jj) * 72 + lane] = v1[jj];
      }
    }
    __syncthreads();

    f32x4 sj[4];
    #pragma unroll
    for (int j = 0; j < 4; ++j) sj[j] = (f32x4)0.f;
    __builtin_amdgcn_s_setprio(1);
    #pragma unroll
    for (int j = 0; j < 4; ++j) {
      int krow = j * 16 + r16;
      s16x8 kf0 = *(const s16x8*)&KsL[krow * 64 + ((g4 ^ (krow & 7)) * 8)];
      s16x8 kf1 = *(const s16x8*)&KsL[krow * 64 + (((4 + g4) ^ (krow & 7)) * 8)];
      sj[j] = __builtin_amdgcn_mfma_f32_16x16x32_bf16(qf0, kf0, sj[j], 0, 0, 0);
      sj[j] = __builtin_amdgcn_mfma_f32_16x16x32_bf16(qf1, kf1, sj[j], 0, 0, 0);
    }
    __builtin_amdgcn_s_setprio(0);

    float alpha_[4];
    #pragma unroll
    for (int rg = 0; rg < 4; ++rg) {
      int qa = q0 + wid * 16 + g4 * 4 + rg;
      float pm = -INFINITY;
      #pragma unroll
      for (int j = 0; j < 4; ++j) {
        int kg = k0 + j * 16 + r16;
        float sv = sj[j][rg] * 0.125f;
        bool bad = (kg >= T_) || (MASKED && kg > qa && kg >= PREFIX_);
        sv = bad ? -INFINITY : sv;
        sj[j][rg] = sv;
        pm = fmaxf(pm, sv);
      }
      pm = fmaxf(pm, __shfl_xor(pm, 1));
      pm = fmaxf(pm, __shfl_xor(pm, 2));
      pm = fmaxf(pm, __shfl_xor(pm, 4));
      pm = fmaxf(pm, __shfl_xor(pm, 8));
      float mn = fmaxf(m_[rg], pm);
      float al = __expf(m_[rg] - mn);
      m_[rg] = mn;
      alpha_[rg] = al;
      int prow = g4 * 4 + rg;
      float ps = 0.f;
      #pragma unroll
      for (int j = 0; j < 4; ++j) {
        float pv = __expf(sj[j][rg] - mn);
        ps += pv;
        PsL[wid][prow * 64 + (((j * 2 + (r16 >> 3)) ^ (prow & 7)) * 8) + (r16 & 7)]
            = f2bf(pv);
      }
      ps += __shfl_xor(ps, 1);
      ps += __shfl_xor(ps, 2);
      ps += __shfl_xor(ps, 4);
      ps += __shfl_xor(ps, 8);
      l_[rg] = l_[rg] * al + ps;
    }
    #pragma unroll
    for (int dj = 0; dj < 4; ++dj)
      #pragma unroll
      for (int rg = 0; rg < 4; ++rg) o_[dj][rg] *= alpha_[rg];

    __builtin_amdgcn_s_setprio(1);
    #pragma unroll
    for (int kk = 0; kk < 2; ++kk) {
      s16x8 pf = *(const s16x8*)
          &PsL[wid][r16 * 64 + (((kk * 4 + g4) ^ (r16 & 7)) * 8)];
      #pragma unroll
      for (int dj = 0; dj < 4; ++dj) {
        s16x8 vf = *(const s16x8*)
            &VtL[(dj * 16 + r16) * 72 + kk * 32 + g4 * 8];
        o_[dj] = __builtin_amdgcn_mfma_f32_16x16x32_bf16(pf, vf, o_[dj], 0, 0, 0);
      }
    }
    __builtin_amdgcn_s_setprio(0);
  }

  #pragma unroll
  for (int rg = 0; rg < 4; ++rg) {
    int qa = q0 + wid * 16 + g4 * 4 + rg;
    if (qa < T_) {
      float inv = 1.f / l_[rg];
      unsigned short* ob = out + (size_t)(b * T_ + qa) * D_ + h * 64;
      #pragma unroll
      for (int dj = 0; dj < 4; ++dj)
        ob[dj * 16 + r16] = f2bf(o_[dj][rg] * inv);
    }
  }
}

// ---------------------------------------------------------------------------
// x = LayerNorm(x + r) * w + b ; writes fp32 x and bf16 shadow xb.
// ---------------------------------------------------------------------------
__global__ __launch_bounds__(256) void ln_res_kernel(
    float* __restrict__ x, const float* __restrict__ r,
    const float* __restrict__ w, const float* __restrict__ b,
    unsigned short* __restrict__ xb) {
  __shared__ float red[4];
  int row = blockIdx.x, tid = threadIdx.x;
  size_t off = (size_t)row * D_ + tid * 4;
  float4 xv = *(float4*)&x[off];
  float4 rv = *(const float4*)&r[off];
  float v0 = xv.x + rv.x, v1 = xv.y + rv.y, v2 = xv.z + rv.z, v3 = xv.w + rv.w;

  float s = v0 + v1 + v2 + v3;
  #pragma unroll
  for (int o = 1; o < 64; o <<= 1) s += __shfl_xor(s, o);
  if ((tid & 63) == 0) red[tid >> 6] = s;
  __syncthreads();
  float mu = (red[0] + red[1] + red[2] + red[3]) * (1.f / 1024.f);
  __syncthreads();

  float d0 = v0 - mu, d1 = v1 - mu, d2 = v2 - mu, d3 = v3 - mu;
  float ss = d0 * d0 + d1 * d1 + d2 * d2 + d3 * d3;
  #pragma unroll
  for (int o = 1; o < 64; o <<= 1) ss += __shfl_xor(ss, o);
  if ((tid & 63) == 0) red[tid >> 6] = ss;
  __syncthreads();
  float var = (red[0] + red[1] + red[2] + red[3]) * (1.f / 1024.f);
  float rs = rsqrtf(var + 1e-5f);

  float4 wv = *(const float4*)&w[tid * 4];
  float4 bv = *(const float4*)&b[tid * 4];
  float o0 = d0 * rs * wv.x + bv.x, o1 = d1 * rs * wv.y + bv.y;
  float o2 = d2 * rs * wv.z + bv.z, o3 = d3 * rs * wv.w + bv.w;
  *(float4*)&x[off] = make_float4(o0, o1, o2, o3);
  unsigned long long pk = (unsigned long long)f2bf(o0)
      | ((unsigned long long)f2bf(o1) << 16)
      | ((unsigned long long)f2bf(o2) << 32)
      | ((unsigned long long)f2bf(o3) << 48);
  *(unsigned long long*)&xb[off] = pk;
}

extern "C" void kernel_launch(void* const* d_in, const int* in_sizes, int n_in,
                              void* d_out, int out_size, void* d_ws, size_t ws_size,
                              hipStream_t stream) {
  const int* text       = (const int*)d_in[0];
  const int* audio      = (const int*)d_in[1];
  const int* enrolled   = (const int*)d_in[2];
  const int* tl_b       = (const int*)d_in[3];
  const int* al_b       = (const int*)d_in[4];
  const float* text_emb = (const float*)d_in[5];
  const float* audio_emb= (const float*)d_in[6];
  const float* sa_in_w  = (const float*)d_in[7];
  const float* sa_in_b  = (const float*)d_in[8];
  const float* sa_out_w = (const float*)d_in[9];
  const float* sa_out_b = (const float*)d_in[10];
  const float* ca_in_w  = (const float*)d_in[11];
  const float* ca_in_b  = (const float*)d_in[12];
  const float* ca_out_w = (const float*)d_in[13];
  const float* ca_out_b = (const float*)d_in[14];
  const float* ff1_w    = (const float*)d_in[15];
  const float* ff1_b    = (const float*)d_in[16];
  const float* ff2_w    = (const float*)d_in[17];
  const float* ff2_b    = (const float*)d_in[18];
  const float* ln1_w    = (const float*)d_in[19];
  const float* ln1_b    = (const float*)d_in[20];
  const float* ln2_w    = (const float*)d_in[21];
  const float* ln2_b    = (const float*)d_in[22];
  const float* ln3_w    = (const float*)d_in[23];
  const float* ln3_b    = (const float*)d_in[24];
  const float* out_w    = (const float*)d_in[25];
  const float* out_b    = (const float*)d_in[26];

  char* p = (char*)d_ws;
  float* xf = (float*)p;            p += (size_t)M_PAD * D_ * 4;
  float* tmp = (float*)p;           p += (size_t)M_PAD * D_ * 4;
  unsigned short* xb = (unsigned short*)p;    p += (size_t)M_PAD * D_ * 2;
  unsigned short* memb = (unsigned short*)p;  p += (size_t)M_PAD * D_ * 2;
  unsigned short* qkv = (unsigned short*)p;   p += (size_t)M_PAD * FF_ * 2;
  unsigned short* attnb = (unsigned short*)p; p += (size_t)M_PAD * D_ * 2;
  unsigned short* wbuf = (unsigned short*)p;  p += (size_t)16777216 * 2;
  unsigned short* outwb = (unsigned short*)p; p += (size_t)1048576 * 2;

  unsigned short* w_sa_qkv = wbuf;
  unsigned short* w_sa_o   = wbuf + 3145728;
  unsigned short* w_ca_qkv = wbuf + 4194304;
  unsigned short* w_ca_o   = wbuf + 7340032;
  unsigned short* w_ff1    = wbuf + 8388608;
  unsigned short* w_ff2    = wbuf + 12582912;

  embed_kernel<<<M_PAD, 256, 0, stream>>>(text, audio, enrolled, tl_b, al_b,
                                          text_emb, audio_emb, xf, xb, memb, attnb);
  cvt_kernel<<<512, 256, 0, stream>>>(out_w, outwb, 131072);

  for (int l = 0; l < L_; ++l) {
    const float* sa_in_w_l  = sa_in_w  + (size_t)l * 3 * D_ * D_;
    const float* sa_in_b_l  = sa_in_b  + (size_t)l * 3 * D_;
    const float* sa_out_w_l = sa_out_w + (size_t)l * D_ * D_;
    const float* sa_out_b_l = sa_out_b + (size_t)l * D_;
    const float* ca_in_w_l  = ca_in_w  + (size_t)l * 3 * D_ * D_;
    const float* ca_in_b_l  = ca_in_b  + (size_t)l * 3 * D_;
    const float* ca_out_w_l = ca_out_w + (size_t)l * D_ * D_;
    const float* ca_out_b_l = ca_out_b + (size_t)l * D_;
    const float* ff1_w_l    = ff1_w    + (size_t)l * FF_ * D_;
    const float* ff1_b_l    = ff1_b    + (size_t)l * FF_;
    const float* ff2_w_l    = ff2_w    + (size_t)l * D_ * FF_;
    const float* ff2_b_l    = ff2_b    + (size_t)l * D_;

    cvt_layer_kernel<<<8192, 256, 0, stream>>>(sa_in_w_l, sa_out_w_l, ca_in_w_l,
                                               ca_out_w_l, ff1_w_l, ff2_w_l, wbuf);

    // ---- self attention ----
    gemm_bf16<128, 128, 0, 1><<<dim3(3 * D_ / 128, M_PAD / 128), 256, 0, stream>>>(
        xb, D_, w_sa_qkv, D_, sa_in_b_l, nullptr, qkv, 3 * D_, M_PAD, D_);
    attn_mfma<true><<<dim3(14, B_ * H_), 256, 0, stream>>>(qkv, attnb);
    gemm_bf16<64, 64, 0, 0><<<dim3(D_ / 64, M_PAD / 64), 256, 0, stream>>>(
        attnb, D_, w_sa_o, D_, sa_out_b_l, tmp, nullptr, D_, M_PAD, D_);
    ln_res_kernel<<<M_TOK, 256, 0, stream>>>(xf, tmp, ln1_w + l * D_, ln1_b + l * D_, xb);

    // ---- cross attention ----
    gemm_bf16<64, 64, 0, 1><<<dim3(D_ / 64, M_PAD / 64), 256, 0, stream>>>(
        xb, D_, w_ca_qkv, D_, ca_in_b_l, nullptr, qkv, 3 * D_, M_PAD, D_);   // q
    gemm_bf16<64, 64, 0, 1><<<dim3(2 * D_ / 64, M_PAD / 64), 256, 0, stream>>>(
        memb, D_, w_ca_qkv + (size_t)D_ * D_, D_, ca_in_b_l + D_,
        nullptr, qkv + D_, 3 * D_, M_PAD, D_);                               // k,v
    attn_mfma<false><<<dim3(14, B_ * H_), 256, 0, stream>>>(qkv, attnb);
    gemm_bf16<64, 64, 0, 0><<<dim3(D_ / 64, M_PAD / 64), 256, 0, stream>>>(
        attnb, D_, w_ca_o, D_, ca_out_b_l, tmp, nullptr, D_, M_PAD, D_);
    ln_res_kernel<<<M_TOK, 256, 0, stream>>>(xf, tmp, ln2_w + l * D_, ln2_b + l * D_, xb);

    // ---- feed forward ----
    gemm_bf16<128, 128, 1, 1><<<dim3(FF_ / 128, M_PAD / 128), 256, 0, stream>>>(
        xb, D_, w_ff1, D_, ff1_b_l, nullptr, qkv, FF_, M_PAD, D_);
    gemm_bf16<64, 64, 0, 0><<<dim3(D_ / 64, M_PAD / 64), 256, 0, stream>>>(
        qkv, FF_, w_ff2, FF_, ff2_b_l, tmp, nullptr, D_, M_PAD, FF_);
    ln_res_kernel<<<M_TOK, 256, 0, stream>>>(xf, tmp, ln3_w + l * D_, ln3_b + l * D_, xb);
  }

  // final projection -> d_out (fp32), only real rows
  gemm_bf16<64, 64, 0, 0><<<dim3(D_ / 64, M_PAD / 64), 256, 0, stream>>>(
      xb, D_, outwb, D_, out_b, (float*)d_out, nullptr, D_, M_TOK, D_);
}

// Round 5
// 2216.214 us; speedup vs baseline: 6.8260x; 1.0325x over previous
//
#include <hip/hip_runtime.h>
#include <hip/hip_bf16.h>

#define B_      4
#define TT_     128
#define TA_     512
#define TE_     225
#define T_      865
#define D_      1024
#define H_      16
#define FF_     4096
#define L_      6
#define PREFIX_ 640
#define M_TOK   (B_ * T_)   // 3460
#define M_PAD   3584        // 28 * 128
#define NKV     (L_ * 2 * D_)   // 12288 concat cross K/V rows

typedef __attribute__((ext_vector_type(8))) short          s16x8;
typedef __attribute__((ext_vector_type(4))) float          f32x4;
typedef __attribute__((ext_vector_type(8))) unsigned short u16x8;

typedef __attribute__((address_space(1))) const void gv_t;
typedef __attribute__((address_space(3))) void       lv_t;

__device__ __forceinline__ float bf2f(unsigned short u) {
  union { unsigned int i; float f; } c; c.i = ((unsigned int)u) << 16; return c.f;
}
__device__ __forceinline__ unsigned short f2bf(float f) {
  union { __hip_bfloat16 h; unsigned short u; } c; c.h = __float2bfloat16(f); return c.u;
}
template <int N> __device__ __forceinline__ void vmwait() {
  asm volatile("s_waitcnt vmcnt(%0)" :: "n"(N) : "memory");
}

// ---------------------------------------------------------------------------
// Embedding + pack + PE. Grid = M_PAD rows; padded rows zero the bf16 bufs.
// ---------------------------------------------------------------------------
__global__ __launch_bounds__(256) void embed_kernel(
    const int* __restrict__ text, const int* __restrict__ audio,
    const int* __restrict__ enrolled, const int* __restrict__ tl_b,
    const int* __restrict__ al_b, const float* __restrict__ text_emb,
    const float* __restrict__ audio_emb,
    float* __restrict__ xf, unsigned short* __restrict__ xb,
    unsigned short* __restrict__ memb, unsigned short* __restrict__ attnb) {
  int row = blockIdx.x;
  int d0 = threadIdx.x * 4;
  size_t off = (size_t)row * D_ + d0;
  if (row >= M_TOK) {
    *(unsigned long long*)&xb[off]    = 0ull;
    *(unsigned long long*)&memb[off]  = 0ull;
    *(unsigned long long*)&attnb[off] = 0ull;
    return;
  }
  int b = row / T_, pos = row - b * T_;
  int tl = tl_b[b], al = al_b[b];
  const float* emb = nullptr;
  int p = 0;
  if (pos < tl) {
    emb = text_emb + (size_t)text[b * TT_ + pos] * D_;
    p = pos;
  } else if (pos < tl + al) {
    emb = audio_emb + (size_t)audio[b * TA_ + (pos - tl)] * D_;
    p = pos - tl;
  } else if (pos < tl + al + TE_) {
    emb = audio_emb + (size_t)enrolled[b * TE_ + (pos - tl - al)] * D_;
    p = pos - tl - al;
  }
  float4 v;
  float* pv = (float*)&v;
  if (emb) {
    const float c = -9.2103403719761836f / (float)D_;  // -ln(10000)/D
    #pragma unroll
    for (int e = 0; e < 4; ++e) {
      int d = d0 + e;
      int i = d >> 1;
      float freq = expf(c * (float)(2 * i));
      float arg = (float)p * freq;
      float pe = (d & 1) ? cosf(arg) : sinf(arg);
      pv[e] = emb[d] + pe;
    }
  } else {
    v = make_float4(0.f, 0.f, 0.f, 0.f);
  }
  *(float4*)&xf[off] = v;
  unsigned long long pk = (unsigned long long)f2bf(pv[0])
      | ((unsigned long long)f2bf(pv[1]) << 16)
      | ((unsigned long long)f2bf(pv[2]) << 32)
      | ((unsigned long long)f2bf(pv[3]) << 48);
  *(unsigned long long*)&xb[off]   = pk;
  *(unsigned long long*)&memb[off] = pk;
}

// ---------------------------------------------------------------------------
// fp32 -> bf16 converters.
// ---------------------------------------------------------------------------
__global__ __launch_bounds__(256) void cvt_kernel(
    const float* __restrict__ in, unsigned short* __restrict__ out, int n8) {
  int i = blockIdx.x * 256 + threadIdx.x;
  if (i >= n8) return;
  const float4* pp = (const float4*)in + (size_t)i * 2;
  float4 a = pp[0], bq = pp[1];
  u16x8 o;
  o[0] = f2bf(a.x);  o[1] = f2bf(a.y);  o[2] = f2bf(a.z);  o[3] = f2bf(a.w);
  o[4] = f2bf(bq.x); o[5] = f2bf(bq.y); o[6] = f2bf(bq.z); o[7] = f2bf(bq.w);
  *(u16x8*)(out + (size_t)i * 8) = o;
}

__global__ __launch_bounds__(256) void cvt_layer_kernel(
    const float* __restrict__ s0, const float* __restrict__ s1,
    const float* __restrict__ s2, const float* __restrict__ s3,
    const float* __restrict__ s4, const float* __restrict__ s5,
    unsigned short* __restrict__ dst) {
  size_t e = ((size_t)blockIdx.x * 256 + threadIdx.x) * 8;
  if (e >= 16777216u) return;
  const float* src; size_t off;
  if      (e <  3145728u) { src = s0; off = e; }
  else if (e <  4194304u) { src = s1; off = e -  3145728u; }
  else if (e <  7340032u) { src = s2; off = e -  4194304u; }
  else if (e <  8388608u) { src = s3; off = e -  7340032u; }
  else if (e < 12582912u) { src = s4; off = e -  8388608u; }
  else                    { src = s5; off = e - 12582912u; }
  const float4* pp = (const float4*)(src + off);
  float4 a = pp[0], bq = pp[1];
  u16x8 o;
  o[0] = f2bf(a.x);  o[1] = f2bf(a.y);  o[2] = f2bf(a.z);  o[3] = f2bf(a.w);
  o[4] = f2bf(bq.x); o[5] = f2bf(bq.y); o[6] = f2bf(bq.z); o[7] = f2bf(bq.w);
  *(u16x8*)(dst + e) = o;
}

// Gather all 6 layers' cross-attn K,V weight rows -> wckv (NKV x D).
__global__ __launch_bounds__(256) void cvt_ckv_w(
    const float* __restrict__ ca_in_w, unsigned short* __restrict__ wckv) {
  int rr = blockIdx.x;            // 0..NKV-1
  int l = rr / (2 * D_), w = rr % (2 * D_);   // D_+w spans k then v rows
  const float* src = ca_in_w + (size_t)l * 3 * D_ * D_ + (size_t)(D_ + w) * D_;
  unsigned short* dst = wckv + (size_t)rr * D_;
  int c = threadIdx.x * 4;
  float4 v4 = *(const float4*)(src + c);
  unsigned long long pk = (unsigned long long)f2bf(v4.x)
      | ((unsigned long long)f2bf(v4.y) << 16)
      | ((unsigned long long)f2bf(v4.z) << 32)
      | ((unsigned long long)f2bf(v4.w) << 48);
  *(unsigned long long*)&dst[c] = pk;
}

__global__ __launch_bounds__(256) void cvt_ckv_b(
    const float* __restrict__ ca_in_b, float* __restrict__ cbias) {
  int rr = blockIdx.x * 256 + threadIdx.x;
  if (rr >= NKV) return;
  int l = rr / (2 * D_), w = rr % (2 * D_);
  cbias[rr] = ca_in_b[(size_t)l * 3 * D_ + D_ + w];
}

// ---------------------------------------------------------------------------
// Depth-2 pipelined bf16 MFMA GEMM: C[M,N] = A[M,K] @ W[N,K]^T + bias.
// 3 LDS buffers, counted vmcnt(4) + raw s_barrier (T4), XOR-swizzled LDS
// (T2, rule #21: inverse-swizzled global source + swizzled read).
// ---------------------------------------------------------------------------
template <int BM, int BN, int BK, int ACT, int OBF>
__global__ __launch_bounds__(256) void gemm_p2(
    const unsigned short* __restrict__ A, int lda,
    const unsigned short* __restrict__ W, int ldw,
    const float* __restrict__ bias,
    float* __restrict__ Cf, unsigned short* __restrict__ Cb, int ldc,
    int Mw, int K) {
  constexpr int WROWS = BM / 2, WCOLS = BN / 2;
  constexpr int WM = WROWS / 16, WN = WCOLS / 16;
  constexpr int LPR = BK / 8;          // lanes per LDS row in one stage inst
  constexpr int RPI = 64 / LPR;        // rows per stage inst
  constexpr int ACH = (BM / 4) / RPI;  // stage insts per wave (A)
  constexpr int BCH = (BN / 4) / RPI;
  constexpr int ABUF = BM * BK, BBUF = BN * BK;
  constexpr int KSUB = BK / 32;
  constexpr int LW = ACH + BCH;        // loads in flight per stage per wave
  __shared__ unsigned short lds[3 * (ABUF + BBUF)];

  int tid = threadIdx.x, lane = tid & 63, wid = tid >> 6;
  // XCD bijective swizzle (m204)
  int gx = gridDim.x;
  int nwg = gx * gridDim.y;
  int orig = blockIdx.y * gx + blockIdx.x;
  int q = nwg >> 3, r = nwg & 7;
  int xcd = orig & 7, loc = orig >> 3;
  int wg = (xcd < r ? xcd * (q + 1) : r * (q + 1) + (xcd - r) * q) + loc;
  int m0 = (wg / gx) * BM, n0 = (wg % gx) * BN;

  int wr = wid >> 1, wc = wid & 1;
  int lrow = lane / LPR, lgrp = lane % LPR;
  int skey = (BK == 32) ? ((lrow >> 1) & 3) : (lrow & 7);
  int lk = (lgrp ^ skey) * 8;          // inverse-swizzled global column group

  const unsigned short* gAp[ACH]; unsigned aoff[ACH];
  const unsigned short* gBp[BCH]; unsigned boff[BCH];
  #pragma unroll
  for (int c = 0; c < ACH; ++c) {
    int row0 = wid * (BM / 4) + c * RPI;
    gAp[c] = A + (size_t)(m0 + row0 + lrow) * lda + lk;
    aoff[c] = row0 * BK;
  }
  #pragma unroll
  for (int c = 0; c < BCH; ++c) {
    int row0 = wid * (BN / 4) + c * RPI;
    gBp[c] = W + (size_t)(n0 + row0 + lrow) * ldw + lk;
    boff[c] = row0 * BK;
  }

  f32x4 acc[WM][WN];
  #pragma unroll
  for (int i = 0; i < WM; ++i)
    #pragma unroll
    for (int j = 0; j < WN; ++j) acc[i][j] = (f32x4)0.f;

  int frow = lane & 15, g4 = lane >> 4;

  auto STAGE = [&](int bi, int t) {
    int k0 = t * BK;
    #pragma unroll
    for (int c = 0; c < ACH; ++c)
      __builtin_amdgcn_global_load_lds((gv_t*)(gAp[c] + k0),
          (lv_t*)&lds[bi * ABUF + aoff[c]], 16, 0, 0);
    #pragma unroll
    for (int c = 0; c < BCH; ++c)
      __builtin_amdgcn_global_load_lds((gv_t*)(gBp[c] + k0),
          (lv_t*)&lds[3 * ABUF + bi * BBUF + boff[c]], 16, 0, 0);
  };

  STAGE(0, 0);
  STAGE(1, 1);
  int nt = K / BK;
  int cur = 0;
  for (int t = 0; t < nt; ++t) {
    if (t + 1 < nt) vmwait<LW>(); else vmwait<0>();  // tile t landed
    __builtin_amdgcn_s_barrier();
    if (t + 2 < nt) {
      int stb = cur + 2; if (stb >= 3) stb -= 3;
      STAGE(stb, t + 2);   // overwrites buffer read at t-1 (safe: post-barrier)
    }
    const unsigned short* Ab = &lds[cur * ABUF];
    const unsigned short* Bb = &lds[3 * ABUF + cur * BBUF];
    #pragma unroll
    for (int kk = 0; kk < KSUB; ++kk) {
      int rk = (BK == 32) ? ((g4 ^ ((frow >> 1) & 3)) * 8)
                          : (((kk * 4 + g4) ^ (frow & 7)) * 8);
      s16x8 af[WM], bfr[WN];
      #pragma unroll
      for (int i = 0; i < WM; ++i)
        af[i] = *(const s16x8*)&Ab[(wr * WROWS + i * 16 + frow) * BK + rk];
      #pragma unroll
      for (int j = 0; j < WN; ++j)
        bfr[j] = *(const s16x8*)&Bb[(wc * WCOLS + j * 16 + frow) * BK + rk];
      __builtin_amdgcn_s_setprio(1);
      #pragma unroll
      for (int i = 0; i < WM; ++i)
        #pragma unroll
        for (int j = 0; j < WN; ++j)
          acc[i][j] = __builtin_amdgcn_mfma_f32_16x16x32_bf16(af[i], bfr[j], acc[i][j], 0, 0, 0);
      __builtin_amdgcn_s_setprio(0);
    }
    cur = (cur == 2) ? 0 : cur + 1;
  }

  // epilogue: C/D layout col=lane&15, row=(lane>>4)*4+reg
  float bv[WN];
  #pragma unroll
  for (int j = 0; j < WN; ++j) bv[j] = bias[n0 + wc * WCOLS + j * 16 + (lane & 15)];
  int rbase = m0 + wr * WROWS + (lane >> 4) * 4;
  int cbase = n0 + wc * WCOLS + (lane & 15);
  #pragma unroll
  for (int i = 0; i < WM; ++i)
    #pragma unroll
    for (int rr = 0; rr < 4; ++rr) {
      int m = rbase + i * 16 + rr;
      if (m < Mw) {
        #pragma unroll
        for (int j = 0; j < WN; ++j) {
          float v = acc[i][j][rr] + bv[j];
          if (ACT) v = fmaxf(v, 0.f);
          if (OBF) Cb[(size_t)m * ldc + cbase + j * 16] = f2bf(v);
          else     Cf[(size_t)m * ldc + cbase + j * 16] = v;
        }
      }
    }
}

// ---------------------------------------------------------------------------
// MFMA flash attention with generic Q / K / V pointers.
// ---------------------------------------------------------------------------
template <bool MASKED>
__global__ __launch_bounds__(256) void attn_mfma(
    const unsigned short* __restrict__ qp, int qld,
    const unsigned short* __restrict__ kp,
    const unsigned short* __restrict__ vp, int kvld,
    unsigned short* __restrict__ out) {
  __shared__ unsigned short KsL[64 * 64];      // [key][d], 16B-groups swizzled
  __shared__ unsigned short VtL[64 * 72];      // [d][key], pad 72
  __shared__ unsigned short PsL[4][16 * 64];   // per-wave P[qrow][key], swizzled
  int tid = threadIdx.x;
  int lane = tid & 63, wid = tid >> 6;
  int b = blockIdx.y >> 4, h = blockIdx.y & 15;
  int q0 = blockIdx.x * 64;
  int r16 = lane & 15, g4 = lane >> 4;

  int qrow = q0 + wid * 16 + r16;
  if (qrow >= T_) qrow = T_ - 1;
  const unsigned short* qbase =
      qp + (size_t)(b * T_ + qrow) * qld + h * 64 + g4 * 8;
  s16x8 qf0 = *(const s16x8*)qbase;
  s16x8 qf1 = *(const s16x8*)(qbase + 32);

  float m_[4], l_[4];
  f32x4 o_[4];
  #pragma unroll
  for (int rg = 0; rg < 4; ++rg) { m_[rg] = -INFINITY; l_[rg] = 0.f; }
  #pragma unroll
  for (int dj = 0; dj < 4; ++dj) o_[dj] = (f32x4)0.f;

  const int nt = MASKED ? max(10, (int)blockIdx.x + 1) : 14;

  for (int t = 0; t < nt; ++t) {
    int k0 = t * 64;
    __syncthreads();

    #pragma unroll
    for (int c = 0; c < 2; ++c) {
      int row = wid * 16 + c * 8 + (lane >> 3);
      int kr = k0 + row; if (kr >= T_) kr = T_ - 1;
      int grp = (lane & 7) ^ (row & 7);
      const unsigned short* src =
          kp + (size_t)(b * T_ + kr) * kvld + h * 64 + grp * 8;
      __builtin_amdgcn_global_load_lds((gv_t*)src,
          (lv_t*)&KsL[(wid * 16 + c * 8) * 64], 16, 0, 0);
    }
    {
      int vkr = k0 + lane; if (vkr >= T_) vkr = T_ - 1;
      const unsigned short* vsrc =
          vp + (size_t)(b * T_ + vkr) * kvld + h * 64 + wid * 16;
      u16x8 v0 = *(const u16x8*)vsrc;
      u16x8 v1 = *(const u16x8*)(vsrc + 8);
      #pragma unroll
      for (int jj = 0; jj < 8; ++jj) {
        VtL[(wid * 16 + jj) * 72 + lane]     = v0[jj];
        VtL[(wid * 16 + 8 + jj) * 72 + lane] = v1[jj];
      }
    }
    __syncthreads();

    f32x4 sj[4];
    #pragma unroll
    for (int j = 0; j < 4; ++j) sj[j] = (f32x4)0.f;
    __builtin_amdgcn_s_setprio(1);
    #pragma unroll
    for (int j = 0; j < 4; ++j) {
      int krow = j * 16 + r16;
      s16x8 kf0 = *(const s16x8*)&KsL[krow * 64 + ((g4 ^ (krow & 7)) * 8)];
      s16x8 kf1 = *(const s16x8*)&KsL[krow * 64 + (((4 + g4) ^ (krow & 7)) * 8)];
      sj[j] = __builtin_amdgcn_mfma_f32_16x16x32_bf16(qf0, kf0, sj[j], 0, 0, 0);
      sj[j] = __builtin_amdgcn_mfma_f32_16x16x32_bf16(qf1, kf1, sj[j], 0, 0, 0);
    }
    __builtin_amdgcn_s_setprio(0);

    float alpha_[4];
    #pragma unroll
    for (int rg = 0; rg < 4; ++rg) {
      int qa = q0 + wid * 16 + g4 * 4 + rg;
      float pm = -INFINITY;
      #pragma unroll
      for (int j = 0; j < 4; ++j) {
        int kg = k0 + j * 16 + r16;
        float sv = sj[j][rg] * 0.125f;
        bool bad = (kg >= T_) || (MASKED && kg > qa && kg >= PREFIX_);
        sv = bad ? -INFINITY : sv;
        sj[j][rg] = sv;
        pm = fmaxf(pm, sv);
      }
      pm = fmaxf(pm, __shfl_xor(pm, 1));
      pm = fmaxf(pm, __shfl_xor(pm, 2));
      pm = fmaxf(pm, __shfl_xor(pm, 4));
      pm = fmaxf(pm, __shfl_xor(pm, 8));
      float mn = fmaxf(m_[rg], pm);
      float al = __expf(m_[rg] - mn);
      m_[rg] = mn;
      alpha_[rg] = al;
      int prow = g4 * 4 + rg;
      float ps = 0.f;
      #pragma unroll
      for (int j = 0; j < 4; ++j) {
        float pv = __expf(sj[j][rg] - mn);
        ps += pv;
        PsL[wid][prow * 64 + (((j * 2 + (r16 >> 3)) ^ (prow & 7)) * 8) + (r16 & 7)]
            = f2bf(pv);
      }
      ps += __shfl_xor(ps, 1);
      ps += __shfl_xor(ps, 2);
      ps += __shfl_xor(ps, 4);
      ps += __shfl_xor(ps, 8);
      l_[rg] = l_[rg] * al + ps;
    }
    #pragma unroll
    for (int dj = 0; dj < 4; ++dj)
      #pragma unroll
      for (int rg = 0; rg < 4; ++rg) o_[dj][rg] *= alpha_[rg];

    __builtin_amdgcn_s_setprio(1);
    #pragma unroll
    for (int kk = 0; kk < 2; ++kk) {
      s16x8 pf = *(const s16x8*)
          &PsL[wid][r16 * 64 + (((kk * 4 + g4) ^ (r16 & 7)) * 8)];
      #pragma unroll
      for (int dj = 0; dj < 4; ++dj) {
        s16x8 vf = *(const s16x8*)
            &VtL[(dj * 16 + r16) * 72 + kk * 32 + g4 * 8];
        o_[dj] = __builtin_amdgcn_mfma_f32_16x16x32_bf16(pf, vf, o_[dj], 0, 0, 0);
      }
    }
    __builtin_amdgcn_s_setprio(0);
  }

  #pragma unroll
  for (int rg = 0; rg < 4; ++rg) {
    int qa = q0 + wid * 16 + g4 * 4 + rg;
    if (qa < T_) {
      float inv = 1.f / l_[rg];
      unsigned short* ob = out + (size_t)(b * T_ + qa) * D_ + h * 64;
      #pragma unroll
      for (int dj = 0; dj < 4; ++dj)
        ob[dj * 16 + r16] = f2bf(o_[dj][rg] * inv);
    }
  }
}

// ---------------------------------------------------------------------------
// x = LayerNorm(x + r) * w + b ; writes fp32 x and bf16 shadow xb.
// ---------------------------------------------------------------------------
__global__ __launch_bounds__(256) void ln_res_kernel(
    float* __restrict__ x, const float* __restrict__ r,
    const float* __restrict__ w, const float* __restrict__ b,
    unsigned short* __restrict__ xb) {
  __shared__ float red[4];
  int row = blockIdx.x, tid = threadIdx.x;
  size_t off = (size_t)row * D_ + tid * 4;
  float4 xv = *(float4*)&x[off];
  float4 rv = *(const float4*)&r[off];
  float v0 = xv.x + rv.x, v1 = xv.y + rv.y, v2 = xv.z + rv.z, v3 = xv.w + rv.w;

  float s = v0 + v1 + v2 + v3;
  #pragma unroll
  for (int o = 1; o < 64; o <<= 1) s += __shfl_xor(s, o);
  if ((tid & 63) == 0) red[tid >> 6] = s;
  __syncthreads();
  float mu = (red[0] + red[1] + red[2] + red[3]) * (1.f / 1024.f);
  __syncthreads();

  float d0 = v0 - mu, d1 = v1 - mu, d2 = v2 - mu, d3 = v3 - mu;
  float ss = d0 * d0 + d1 * d1 + d2 * d2 + d3 * d3;
  #pragma unroll
  for (int o = 1; o < 64; o <<= 1) ss += __shfl_xor(ss, o);
  if ((tid & 63) == 0) red[tid >> 6] = ss;
  __syncthreads();
  float var = (red[0] + red[1] + red[2] + red[3]) * (1.f / 1024.f);
  float rs = rsqrtf(var + 1e-5f);

  float4 wv = *(const float4*)&w[tid * 4];
  float4 bv = *(const float4*)&b[tid * 4];
  float o0 = d0 * rs * wv.x + bv.x, o1 = d1 * rs * wv.y + bv.y;
  float o2 = d2 * rs * wv.z + bv.z, o3 = d3 * rs * wv.w + bv.w;
  *(float4*)&x[off] = make_float4(o0, o1, o2, o3);
  unsigned long long pk = (unsigned long long)f2bf(o0)
      | ((unsigned long long)f2bf(o1) << 16)
      | ((unsigned long long)f2bf(o2) << 32)
      | ((unsigned long long)f2bf(o3) << 48);
  *(unsigned long long*)&xb[off] = pk;
}

extern "C" void kernel_launch(void* const* d_in, const int* in_sizes, int n_in,
                              void* d_out, int out_size, void* d_ws, size_t ws_size,
                              hipStream_t stream) {
  const int* text       = (const int*)d_in[0];
  const int* audio      = (const int*)d_in[1];
  const int* enrolled   = (const int*)d_in[2];
  const int* tl_b       = (const int*)d_in[3];
  const int* al_b       = (const int*)d_in[4];
  const float* text_emb = (const float*)d_in[5];
  const float* audio_emb= (const float*)d_in[6];
  const float* sa_in_w  = (const float*)d_in[7];
  const float* sa_in_b  = (const float*)d_in[8];
  const float* sa_out_w = (const float*)d_in[9];
  const float* sa_out_b = (const float*)d_in[10];
  const float* ca_in_w  = (const float*)d_in[11];
  const float* ca_in_b  = (const float*)d_in[12];
  const float* ca_out_w = (const float*)d_in[13];
  const float* ca_out_b = (const float*)d_in[14];
  const float* ff1_w    = (const float*)d_in[15];
  const float* ff1_b    = (const float*)d_in[16];
  const float* ff2_w    = (const float*)d_in[17];
  const float* ff2_b    = (const float*)d_in[18];
  const float* ln1_w    = (const float*)d_in[19];
  const float* ln1_b    = (const float*)d_in[20];
  const float* ln2_w    = (const float*)d_in[21];
  const float* ln2_b    = (const float*)d_in[22];
  const float* ln3_w    = (const float*)d_in[23];
  const float* ln3_b    = (const float*)d_in[24];
  const float* out_w    = (const float*)d_in[25];
  const float* out_b    = (const float*)d_in[26];

  char* p = (char*)d_ws;
  float* xf = (float*)p;            p += (size_t)M_PAD * D_ * 4;
  float* tmp = (float*)p;           p += (size_t)M_PAD * D_ * 4;
  unsigned short* xb = (unsigned short*)p;    p += (size_t)M_PAD * D_ * 2;
  unsigned short* memb = (unsigned short*)p;  p += (size_t)M_PAD * D_ * 2;
  unsigned short* qkv = (unsigned short*)p;   p += (size_t)M_PAD * FF_ * 2;
  unsigned short* attnb = (unsigned short*)p; p += (size_t)M_PAD * D_ * 2;
  unsigned short* wbuf = (unsigned short*)p;  p += (size_t)16777216 * 2;
  unsigned short* outwb = (unsigned short*)p; p += (size_t)1048576 * 2;
  // fused cross-KV extras (gated on ws_size)
  unsigned short* ckv  = (unsigned short*)p;  p += (size_t)M_PAD * NKV * 2;
  unsigned short* wckv = (unsigned short*)p;  p += (size_t)NKV * D_ * 2;
  float* cbias = (float*)p;                   p += (size_t)NKV * 4;
  bool fused = ((size_t)(p - (char*)d_ws)) <= ws_size;

  unsigned short* w_sa_qkv = wbuf;
  unsigned short* w_sa_o   = wbuf + 3145728;
  unsigned short* w_ca_qkv = wbuf + 4194304;
  unsigned short* w_ca_o   = wbuf + 7340032;
  unsigned short* w_ff1    = wbuf + 8388608;
  unsigned short* w_ff2    = wbuf + 12582912;

  embed_kernel<<<M_PAD, 256, 0, stream>>>(text, audio, enrolled, tl_b, al_b,
                                          text_emb, audio_emb, xf, xb, memb, attnb);
  cvt_kernel<<<512, 256, 0, stream>>>(out_w, outwb, 131072);

  if (fused) {
    cvt_ckv_w<<<NKV, 256, 0, stream>>>(ca_in_w, wckv);
    cvt_ckv_b<<<NKV / 256, 256, 0, stream>>>(ca_in_b, cbias);
    // all-layer cross K/V: (M_PAD x NKV) = memb @ wckv^T + cbias
    gemm_p2<128, 128, 32, 0, 1><<<dim3(NKV / 128, M_PAD / 128), 256, 0, stream>>>(
        memb, D_, wckv, D_, cbias, nullptr, ckv, NKV, M_PAD, D_);
  }

  for (int l = 0; l < L_; ++l) {
    const float* sa_in_w_l  = sa_in_w  + (size_t)l * 3 * D_ * D_;
    const float* sa_in_b_l  = sa_in_b  + (size_t)l * 3 * D_;
    const float* sa_out_w_l = sa_out_w + (size_t)l * D_ * D_;
    const float* sa_out_b_l = sa_out_b + (size_t)l * D_;
    const float* ca_in_w_l  = ca_in_w  + (size_t)l * 3 * D_ * D_;
    const float* ca_in_b_l  = ca_in_b  + (size_t)l * 3 * D_;
    const float* ca_out_w_l = ca_out_w + (size_t)l * D_ * D_;
    const float* ca_out_b_l = ca_out_b + (size_t)l * D_;
    const float* ff1_w_l    = ff1_w    + (size_t)l * FF_ * D_;
    const float* ff1_b_l    = ff1_b    + (size_t)l * FF_;
    const float* ff2_w_l    = ff2_w    + (size_t)l * D_ * FF_;
    const float* ff2_b_l    = ff2_b    + (size_t)l * D_;

    cvt_layer_kernel<<<8192, 256, 0, stream>>>(sa_in_w_l, sa_out_w_l, ca_in_w_l,
                                               ca_out_w_l, ff1_w_l, ff2_w_l, wbuf);

    // ---- self attention ----
    gemm_p2<128, 128, 32, 0, 1><<<dim3(3 * D_ / 128, M_PAD / 128), 256, 0, stream>>>(
        xb, D_, w_sa_qkv, D_, sa_in_b_l, nullptr, qkv, 3 * D_, M_PAD, D_);
    attn_mfma<true><<<dim3(14, B_ * H_), 256, 0, stream>>>(
        qkv, 3 * D_, qkv + D_, qkv + 2 * D_, 3 * D_, attnb);
    gemm_p2<64, 64, 64, 0, 0><<<dim3(D_ / 64, M_PAD / 64), 256, 0, stream>>>(
        attnb, D_, w_sa_o, D_, sa_out_b_l, tmp, nullptr, D_, M_PAD, D_);
    ln_res_kernel<<<M_TOK, 256, 0, stream>>>(xf, tmp, ln1_w + l * D_, ln1_b + l * D_, xb);

    // ---- cross attention ----
    gemm_p2<64, 64, 64, 0, 1><<<dim3(D_ / 64, M_PAD / 64), 256, 0, stream>>>(
        xb, D_, w_ca_qkv, D_, ca_in_b_l, nullptr, qkv, 3 * D_, M_PAD, D_);   // q
    if (fused) {
      attn_mfma<false><<<dim3(14, B_ * H_), 256, 0, stream>>>(
          qkv, 3 * D_, ckv + (size_t)l * 2 * D_, ckv + (size_t)l * 2 * D_ + D_,
          NKV, attnb);
    } else {
      gemm_p2<64, 64, 64, 0, 1><<<dim3(2 * D_ / 64, M_PAD / 64), 256, 0, stream>>>(
          memb, D_, w_ca_qkv + (size_t)D_ * D_, D_, ca_in_b_l + D_,
          nullptr, qkv + D_, 3 * D_, M_PAD, D_);
      attn_mfma<false><<<dim3(14, B_ * H_), 256, 0, stream>>>(
          qkv, 3 * D_, qkv + D_, qkv + 2 * D_, 3 * D_, attnb);
    }
    gemm_p2<64, 64, 64, 0, 0><<<dim3(D_ / 64, M_PAD / 64), 256, 0, stream>>>(
        attnb, D_, w_ca_o, D_, ca_out_b_l, tmp, nullptr, D_, M_PAD, D_);
    ln_res_kernel<<<M_TOK, 256, 0, stream>>>(xf, tmp, ln2_w + l * D_, ln2_b + l * D_, xb);

    // ---- feed forward ----
    gemm_p2<128, 128, 32, 1, 1><<<dim3(FF_ / 128, M_PAD / 128), 256, 0, stream>>>(
        xb, D_, w_ff1, D_, ff1_b_l, nullptr, qkv, FF_, M_PAD, D_);
    gemm_p2<64, 64, 64, 0, 0><<<dim3(D_ / 64, M_PAD / 64), 256, 0, stream>>>(
        qkv, FF_, w_ff2, FF_, ff2_b_l, tmp, nullptr, D_, M_PAD, FF_);
    ln_res_kernel<<<M_TOK, 256, 0, stream>>>(xf, tmp, ln3_w + l * D_, ln3_b + l * D_, xb);
  }

  // final projection -> d_out (fp32), only real rows
  gemm_p2<64, 64, 64, 0, 0><<<dim3(D_ / 64, M_PAD / 64), 256, 0, stream>>>(
      xb, D_, outwb, D_, out_b, (float*)d_out, nullptr, D_, M_TOK, D_);
}